// Round 1
// baseline (300.974 us; speedup 1.0000x reference)
//
#include <hip/hip_runtime.h>

typedef __attribute__((ext_vector_type(8))) short short8;
typedef __attribute__((ext_vector_type(4))) float floatx4;

#define HIDDEN 768
#define NH 12
#define HD 64
#define SEQ 2048
#define BATCH 2
#define BHN (BATCH*NH)      // 24
#define MTOT (BATCH*SEQ)    // 4096
#define NQKV (3*HIDDEN)     // 2304
#define LDT 40              // BK(32) + 8 pad, keeps 16B alignment (80B row stride)

__device__ __forceinline__ short f2bf(float f) {
  union { float f; unsigned u; } v; v.f = f;
  unsigned r = v.u + 0x7FFFu + ((v.u >> 16) & 1u);   // RNE
  return (short)(r >> 16);
}

__device__ __forceinline__ floatx4 mfma_bf16(short8 a, short8 b, floatx4 c) {
  return __builtin_amdgcn_mfma_f32_16x16x32_bf16(a, b, c, 0, 0, 0);
}

// ---------------- weight transpose + fp32->bf16 ----------------
// W [K][N] fp32  ->  WT [N][K] bf16.  Grid: (N/64, K/64), 256 threads.
__global__ __launch_bounds__(256) void transpose_cvt(const float* __restrict__ W,
                                                     short* __restrict__ WT,
                                                     int K, int N) {
  __shared__ short t[64][72];   // pad 72 to break bank alignment
  int nb = blockIdx.x * 64, kb = blockIdx.y * 64;
  int tid = threadIdx.x;
  {
    int k  = tid >> 2;            // 0..63
    int n0 = (tid & 3) << 4;      // 0,16,32,48
    const float4* src = reinterpret_cast<const float4*>(W + (size_t)(kb + k) * N + nb + n0);
    #pragma unroll
    for (int c = 0; c < 4; ++c) {
      float4 v = src[c];
      t[n0 + c*4 + 0][k] = f2bf(v.x);
      t[n0 + c*4 + 1][k] = f2bf(v.y);
      t[n0 + c*4 + 2][k] = f2bf(v.z);
      t[n0 + c*4 + 3][k] = f2bf(v.w);
    }
  }
  __syncthreads();
  {
    int n  = tid >> 2;
    int k0 = (tid & 3) << 4;
    const short8* row = reinterpret_cast<const short8*>(&t[n][k0]);  // 144n+32m: 16B aligned
    short8* dst = reinterpret_cast<short8*>(WT + (size_t)(nb + n) * K + kb + k0);
    dst[0] = row[0];
    dst[1] = row[1];
  }
}

// ---------------- GEMM1: qkv = x @ W_qkv + b, scatter to Q(,/8)/K/V^T bf16 ----------------
// Grid (4096/128, 2304/128) = (32,18), 256 threads = 4 waves (2x2 of 64x64).
__global__ __launch_bounds__(256) void gemm_qkv(const float* __restrict__ X,
                                                const short* __restrict__ WT,
                                                const float* __restrict__ bias,
                                                short* __restrict__ Qb,
                                                short* __restrict__ Kb,
                                                short* __restrict__ VTb) {
  __shared__ short As[128 * LDT];
  __shared__ short Bs[128 * LDT];
  int m0 = blockIdx.x * 128, n0 = blockIdx.y * 128;
  int tid = threadIdx.x;
  int lane = tid & 63, wv = tid >> 6;
  int wm = (wv >> 1) << 6, wn = (wv & 1) << 6;
  int quad = lane >> 4, l16 = lane & 15;
  floatx4 acc[4][4] = {};
  for (int kk = 0; kk < HIDDEN; kk += 32) {
    __syncthreads();
    #pragma unroll
    for (int c = 0; c < 2; ++c) {
      int idx = (tid + c * 256) * 8;
      int r = idx >> 5, col = idx & 31;
      const float4* sa = reinterpret_cast<const float4*>(X + (size_t)(m0 + r) * HIDDEN + kk + col);
      float4 v0 = sa[0], v1 = sa[1];
      short8 av;
      av[0] = f2bf(v0.x); av[1] = f2bf(v0.y); av[2] = f2bf(v0.z); av[3] = f2bf(v0.w);
      av[4] = f2bf(v1.x); av[5] = f2bf(v1.y); av[6] = f2bf(v1.z); av[7] = f2bf(v1.w);
      *reinterpret_cast<short8*>(&As[r * LDT + col]) = av;
      *reinterpret_cast<short8*>(&Bs[r * LDT + col]) =
          *reinterpret_cast<const short8*>(WT + (size_t)(n0 + r) * HIDDEN + kk + col);
    }
    __syncthreads();
    short8 af[4], bfr[4];
    #pragma unroll
    for (int i = 0; i < 4; ++i)
      af[i] = *reinterpret_cast<const short8*>(&As[(wm + i * 16 + l16) * LDT + quad * 8]);
    #pragma unroll
    for (int j = 0; j < 4; ++j)
      bfr[j] = *reinterpret_cast<const short8*>(&Bs[(wn + j * 16 + l16) * LDT + quad * 8]);
    #pragma unroll
    for (int i = 0; i < 4; ++i)
      #pragma unroll
      for (int j = 0; j < 4; ++j)
        acc[i][j] = mfma_bf16(af[i], bfr[j], acc[i][j]);
  }
  // epilogue: bias, split into Q (scaled 1/8), K, V^T
  int colbase = n0 + wn;
  int part = colbase / HIDDEN;   // uniform per wave (128 | 768)
  #pragma unroll
  for (int j = 0; j < 4; ++j) {
    int col = colbase + j * 16 + l16;
    float bs = bias[col];
    int rem = col - part * HIDDEN;
    int h = rem >> 6, d = rem & 63;
    #pragma unroll
    for (int i = 0; i < 4; ++i) {
      #pragma unroll
      for (int r = 0; r < 4; ++r) {
        int row = m0 + wm + i * 16 + quad * 4 + r;
        float v = acc[i][j][r] + bs;
        int bb = row >> 11, s = row & 2047;
        int bh = bb * NH + h;
        if (part == 0) {
          Qb[((size_t)bh * SEQ + s) * HD + d] = f2bf(v * 0.125f);   // fold 1/sqrt(64), exact
        } else if (part == 1) {
          Kb[((size_t)bh * SEQ + s) * HD + d] = f2bf(v);
        } else {
          VTb[((size_t)bh * HD + d) * SEQ + s] = f2bf(v);
        }
      }
    }
  }
}

// ---------------- flash attention, causal. One 16-row Q-tile per wave ----------------
// S^T = K.Q^T (C-layout: row=kv, col=q) -> online softmax via shfl_xor(16/32)
// -> P^T remapped in-register to B-operand (K=32) -> O^T = V^T . P^T.
// Grid (2048/64, 24), 256 threads = 4 waves.
__global__ __launch_bounds__(256) void attn_fwd(const short* __restrict__ Qb,
                                                const short* __restrict__ Kb,
                                                const short* __restrict__ VTb,
                                                short* __restrict__ AO) {
  int bh = blockIdx.y;
  int b = bh / NH, h = bh % NH;
  int wv = threadIdx.x >> 6;
  int lane = threadIdx.x & 63;
  int quad = lane >> 4, l16 = lane & 15;
  int qbase = blockIdx.x * 64 + wv * 16;
  const short* Qp = Qb + (size_t)bh * SEQ * HD;
  const short* Kp = Kb + (size_t)bh * SEQ * HD;
  const short* Vp = VTb + (size_t)bh * HD * SEQ;

  // Q fragment as B-operand of K.Q^T: B[k=d][n=q] -> lane holds Q[qbase+l16][quad*8..+7 (+32)]
  short8 bq0 = *reinterpret_cast<const short8*>(Qp + (qbase + l16) * HD + quad * 8);
  short8 bq1 = *reinterpret_cast<const short8*>(Qp + (qbase + l16) * HD + 32 + quad * 8);

  floatx4 o0 = {}, o1 = {}, o2 = {}, o3 = {};   // O^T[d-tile][.], C-layout, col=q=l16
  float m_run = -1e30f, l_run = 0.f;
  int nkv = qbase + 16;          // causal: kv <= q <= qbase+15
  int n32 = (nkv + 31) >> 5;

  for (int kt = 0; kt < n32; ++kt) {
    int kb = kt << 5;
    // K as A-operand: A[m=kv][k=d]
    const short* kp0 = Kp + (kb + l16) * HD + quad * 8;
    const short* kp1 = kp0 + 16 * HD;
    short8 ka00 = *reinterpret_cast<const short8*>(kp0);
    short8 ka01 = *reinterpret_cast<const short8*>(kp0 + 32);
    short8 ka10 = *reinterpret_cast<const short8*>(kp1);
    short8 ka11 = *reinterpret_cast<const short8*>(kp1 + 32);
    floatx4 st0 = {}, st1 = {};
    st0 = mfma_bf16(ka00, bq0, st0);
    st0 = mfma_bf16(ka01, bq1, st0);
    st1 = mfma_bf16(ka10, bq0, st1);
    st1 = mfma_bf16(ka11, bq1, st1);
    // causal mask (only the last kv-tile can cross the diagonal)
    if (kt == n32 - 1) {
      int q = qbase + l16;
      #pragma unroll
      for (int r = 0; r < 4; ++r) {
        if (kb + quad * 4 + r > q)      st0[r] = -1e30f;
        if (kb + 16 + quad * 4 + r > q) st1[r] = -1e30f;
      }
    }
    // online softmax over column q = l16 (reduce across the 4 quads)
    float mloc = fmaxf(fmaxf(fmaxf(st0[0], st0[1]), fmaxf(st0[2], st0[3])),
                       fmaxf(fmaxf(st1[0], st1[1]), fmaxf(st1[2], st1[3])));
    mloc = fmaxf(mloc, __shfl_xor(mloc, 16));
    mloc = fmaxf(mloc, __shfl_xor(mloc, 32));
    float m_new = fmaxf(m_run, mloc);
    float p0[4], p1[4];
    float sloc = 0.f;
    #pragma unroll
    for (int r = 0; r < 4; ++r) { p0[r] = __expf(st0[r] - m_new); sloc += p0[r]; }
    #pragma unroll
    for (int r = 0; r < 4; ++r) { p1[r] = __expf(st1[r] - m_new); sloc += p1[r]; }
    sloc += __shfl_xor(sloc, 16);
    sloc += __shfl_xor(sloc, 32);
    float alpha = __expf(m_run - m_new);
    l_run = l_run * alpha + sloc;
    m_run = m_new;
    o0 *= alpha; o1 *= alpha; o2 *= alpha; o3 *= alpha;
    // remap P^T (C-layout, kv=quad*4+r per 16-tile) -> B-operand K=32 (kv=quad*8+j)
    short8 pb;
    int hi = quad >> 1;
    int sb = (quad & 1) << 1;
    #pragma unroll
    for (int j = 0; j < 8; ++j) {
      int srcl = ((sb + (j >> 2)) << 4) + l16;
      float va = __shfl(p0[j & 3], srcl);
      float vb = __shfl(p1[j & 3], srcl);
      pb[j] = f2bf(hi ? vb : va);
    }
    // O^T += V^T . P^T : A[m=d][k=kv] from V^T (d-contiguous rows of length SEQ)
    const short* vp = Vp + l16 * SEQ + kb + quad * 8;
    short8 va0 = *reinterpret_cast<const short8*>(vp);
    short8 va1 = *reinterpret_cast<const short8*>(vp + 16 * SEQ);
    short8 va2 = *reinterpret_cast<const short8*>(vp + 32 * SEQ);
    short8 va3 = *reinterpret_cast<const short8*>(vp + 48 * SEQ);
    o0 = mfma_bf16(va0, pb, o0);
    o1 = mfma_bf16(va1, pb, o1);
    o2 = mfma_bf16(va2, pb, o2);
    o3 = mfma_bf16(va3, pb, o3);
  }
  float inv = 1.f / l_run;
  int s = qbase + l16;
  size_t outbase = ((size_t)(b * SEQ + s)) * HIDDEN + h * HD;
  #pragma unroll
  for (int r = 0; r < 4; ++r) {
    AO[outbase + 0  + quad * 4 + r] = f2bf(o0[r] * inv);
    AO[outbase + 16 + quad * 4 + r] = f2bf(o1[r] * inv);
    AO[outbase + 32 + quad * 4 + r] = f2bf(o2[r] * inv);
    AO[outbase + 48 + quad * 4 + r] = f2bf(o3[r] * inv);
  }
}

// ---------------- GEMM2: out = AO @ W_out + b_out (fp32 out) ----------------
// Grid (32, 6), 256 threads.
__global__ __launch_bounds__(256) void gemm_out(const short* __restrict__ AO,
                                                const short* __restrict__ WT,
                                                const float* __restrict__ bias,
                                                float* __restrict__ out) {
  __shared__ short As[128 * LDT];
  __shared__ short Bs[128 * LDT];
  int m0 = blockIdx.x * 128, n0 = blockIdx.y * 128;
  int tid = threadIdx.x;
  int lane = tid & 63, wv = tid >> 6;
  int wm = (wv >> 1) << 6, wn = (wv & 1) << 6;
  int quad = lane >> 4, l16 = lane & 15;
  floatx4 acc[4][4] = {};
  for (int kk = 0; kk < HIDDEN; kk += 32) {
    __syncthreads();
    #pragma unroll
    for (int c = 0; c < 2; ++c) {
      int idx = (tid + c * 256) * 8;
      int r = idx >> 5, col = idx & 31;
      *reinterpret_cast<short8*>(&As[r * LDT + col]) =
          *reinterpret_cast<const short8*>(AO + (size_t)(m0 + r) * HIDDEN + kk + col);
      *reinterpret_cast<short8*>(&Bs[r * LDT + col]) =
          *reinterpret_cast<const short8*>(WT + (size_t)(n0 + r) * HIDDEN + kk + col);
    }
    __syncthreads();
    short8 af[4], bfr[4];
    #pragma unroll
    for (int i = 0; i < 4; ++i)
      af[i] = *reinterpret_cast<const short8*>(&As[(wm + i * 16 + l16) * LDT + quad * 8]);
    #pragma unroll
    for (int j = 0; j < 4; ++j)
      bfr[j] = *reinterpret_cast<const short8*>(&Bs[(wn + j * 16 + l16) * LDT + quad * 8]);
    #pragma unroll
    for (int i = 0; i < 4; ++i)
      #pragma unroll
      for (int j = 0; j < 4; ++j)
        acc[i][j] = mfma_bf16(af[i], bfr[j], acc[i][j]);
  }
  #pragma unroll
  for (int j = 0; j < 4; ++j) {
    int col = n0 + wn + j * 16 + l16;
    float bs = bias[col];
    #pragma unroll
    for (int i = 0; i < 4; ++i) {
      #pragma unroll
      for (int r = 0; r < 4; ++r) {
        int row = m0 + wm + i * 16 + quad * 4 + r;
        out[(size_t)row * HIDDEN + col] = acc[i][j][r] + bs;
      }
    }
  }
}

extern "C" void kernel_launch(void* const* d_in, const int* in_sizes, int n_in,
                              void* d_out, int out_size, void* d_ws, size_t ws_size,
                              hipStream_t stream) {
  const float* x    = (const float*)d_in[0];   // [2,2048,768]
  const float* Wqkv = (const float*)d_in[1];   // [768,2304]
  const float* bqkv = (const float*)d_in[2];   // [2304]
  const float* Wout = (const float*)d_in[3];   // [768,768]
  const float* bout = (const float*)d_in[4];   // [768]
  float* out = (float*)d_out;

  short* WqkvT = (short*)d_ws;                     // [2304][768] bf16
  short* WoutT = WqkvT + (size_t)NQKV * HIDDEN;    // [768][768]
  short* Qb    = WoutT + (size_t)HIDDEN * HIDDEN;  // [24][2048][64] (pre-scaled by 1/8)
  short* Kb    = Qb + (size_t)BHN * SEQ * HD;      // [24][2048][64]
  short* VTb   = Kb + (size_t)BHN * SEQ * HD;      // [24][64][2048]
  short* AO    = VTb + (size_t)BHN * SEQ * HD;     // [4096][768]
  // total ws used: ~29.9 MB

  transpose_cvt<<<dim3(NQKV / 64, HIDDEN / 64), 256, 0, stream>>>(Wqkv, WqkvT, HIDDEN, NQKV);
  transpose_cvt<<<dim3(HIDDEN / 64, HIDDEN / 64), 256, 0, stream>>>(Wout, WoutT, HIDDEN, HIDDEN);
  gemm_qkv<<<dim3(MTOT / 128, NQKV / 128), 256, 0, stream>>>(x, WqkvT, bqkv, Qb, Kb, VTb);
  attn_fwd<<<dim3(SEQ / 64, BHN), 256, 0, stream>>>(Qb, Kb, VTb, AO);
  gemm_out<<<dim3(MTOT / 128, HIDDEN / 128), 256, 0, stream>>>(AO, WoutT, bout, out);
}

// Round 2
// 261.531 us; speedup vs baseline: 1.1508x; 1.1508x over previous
//
#include <hip/hip_runtime.h>

typedef __attribute__((ext_vector_type(8))) short short8;
typedef __attribute__((ext_vector_type(4))) float floatx4;

#define HIDDEN 768
#define NH 12
#define HD 64
#define SEQ 2048
#define BATCH 2
#define BHN (BATCH*NH)      // 24
#define MTOT (BATCH*SEQ)    // 4096
#define NQKV (3*HIDDEN)     // 2304
#define LDT 40              // BK(32) + 8 pad, keeps 16B alignment (80B row stride)

__device__ __forceinline__ short f2bf(float f) {
  union { float f; unsigned u; } v; v.f = f;
  unsigned r = v.u + 0x7FFFu + ((v.u >> 16) & 1u);   // RNE
  return (short)(r >> 16);
}

__device__ __forceinline__ floatx4 mfma_bf16(short8 a, short8 b, floatx4 c) {
  return __builtin_amdgcn_mfma_f32_16x16x32_bf16(a, b, c, 0, 0, 0);
}

// ---------------- weight transpose + fp32->bf16 ----------------
// W [K][N] fp32  ->  WT [N][K] bf16.  Grid: (N/64, K/64), 256 threads.
__global__ __launch_bounds__(256) void transpose_cvt(const float* __restrict__ W,
                                                     short* __restrict__ WT,
                                                     int K, int N) {
  __shared__ short t[64][72];   // pad 72 to break bank alignment
  int nb = blockIdx.x * 64, kb = blockIdx.y * 64;
  int tid = threadIdx.x;
  {
    int k  = tid >> 2;            // 0..63
    int n0 = (tid & 3) << 4;      // 0,16,32,48
    const float4* src = reinterpret_cast<const float4*>(W + (size_t)(kb + k) * N + nb + n0);
    #pragma unroll
    for (int c = 0; c < 4; ++c) {
      float4 v = src[c];
      t[n0 + c*4 + 0][k] = f2bf(v.x);
      t[n0 + c*4 + 1][k] = f2bf(v.y);
      t[n0 + c*4 + 2][k] = f2bf(v.z);
      t[n0 + c*4 + 3][k] = f2bf(v.w);
    }
  }
  __syncthreads();
  {
    int n  = tid >> 2;
    int k0 = (tid & 3) << 4;
    const short8* row = reinterpret_cast<const short8*>(&t[n][k0]);
    short8* dst = reinterpret_cast<short8*>(WT + (size_t)(nb + n) * K + kb + k0);
    dst[0] = row[0];
    dst[1] = row[1];
  }
}

// ---------------- GEMM1: qkv = x @ W_qkv + b, scatter to Q(,/8)/K/V^T bf16 ----------------
// Grid (4096/128, 2304/128) = (32,18), 256 threads = 4 waves (2x2 of 64x64).
__global__ __launch_bounds__(256) void gemm_qkv(const float* __restrict__ X,
                                                const short* __restrict__ WT,
                                                const float* __restrict__ bias,
                                                short* __restrict__ Qb,
                                                short* __restrict__ Kb,
                                                short* __restrict__ VTb) {
  __shared__ short As[128 * LDT];
  __shared__ short Bs[128 * LDT];
  int m0 = blockIdx.x * 128, n0 = blockIdx.y * 128;
  int tid = threadIdx.x;
  int lane = tid & 63, wv = tid >> 6;
  int wm = (wv >> 1) << 6, wn = (wv & 1) << 6;
  int quad = lane >> 4, l16 = lane & 15;
  floatx4 acc[4][4] = {};
  for (int kk = 0; kk < HIDDEN; kk += 32) {
    __syncthreads();
    #pragma unroll
    for (int c = 0; c < 2; ++c) {
      int idx = (tid + c * 256) * 8;
      int r = idx >> 5, col = idx & 31;
      const float4* sa = reinterpret_cast<const float4*>(X + (size_t)(m0 + r) * HIDDEN + kk + col);
      float4 v0 = sa[0], v1 = sa[1];
      short8 av;
      av[0] = f2bf(v0.x); av[1] = f2bf(v0.y); av[2] = f2bf(v0.z); av[3] = f2bf(v0.w);
      av[4] = f2bf(v1.x); av[5] = f2bf(v1.y); av[6] = f2bf(v1.z); av[7] = f2bf(v1.w);
      *reinterpret_cast<short8*>(&As[r * LDT + col]) = av;
      *reinterpret_cast<short8*>(&Bs[r * LDT + col]) =
          *reinterpret_cast<const short8*>(WT + (size_t)(n0 + r) * HIDDEN + kk + col);
    }
    __syncthreads();
    short8 af[4], bfr[4];
    #pragma unroll
    for (int i = 0; i < 4; ++i)
      af[i] = *reinterpret_cast<const short8*>(&As[(wm + i * 16 + l16) * LDT + quad * 8]);
    #pragma unroll
    for (int j = 0; j < 4; ++j)
      bfr[j] = *reinterpret_cast<const short8*>(&Bs[(wn + j * 16 + l16) * LDT + quad * 8]);
    #pragma unroll
    for (int i = 0; i < 4; ++i)
      #pragma unroll
      for (int j = 0; j < 4; ++j)
        acc[i][j] = mfma_bf16(af[i], bfr[j], acc[i][j]);
  }
  // epilogue: bias, split into Q (scaled 1/8), K, V^T
  int colbase = n0 + wn;
  int part = colbase / HIDDEN;   // uniform per wave (128 | 768)
  #pragma unroll
  for (int j = 0; j < 4; ++j) {
    int col = colbase + j * 16 + l16;
    float bs = bias[col];
    int rem = col - part * HIDDEN;
    int h = rem >> 6, d = rem & 63;
    #pragma unroll
    for (int i = 0; i < 4; ++i) {
      #pragma unroll
      for (int r = 0; r < 4; ++r) {
        int row = m0 + wm + i * 16 + quad * 4 + r;
        float v = acc[i][j][r] + bs;
        int bb = row >> 11, s = row & 2047;
        int bh = bb * NH + h;
        if (part == 0) {
          Qb[((size_t)bh * SEQ + s) * HD + d] = f2bf(v * 0.125f);   // fold 1/sqrt(64), exact
        } else if (part == 1) {
          Kb[((size_t)bh * SEQ + s) * HD + d] = f2bf(v);
        } else {
          VTb[((size_t)bh * HD + d) * SEQ + s] = f2bf(v);
        }
      }
    }
  }
}

// ---------------- flash attention, causal, split-kv within block ----------------
// One block per 16-row Q-tile. 4 waves process interleaved 32-kv tiles with
// private online-softmax state (m,l,O^T), then merge partials via LDS.
// S^T = K.Q^T (C-layout: row=kv, col=q); P^T remapped in-register (packed,
// 8 shfls) to B-operand; O^T = V^T . P^T.
// Grid (2048/16, 24), 256 threads = 4 waves. qt reversed so heavy blocks go first.
__global__ __launch_bounds__(256) void attn_fwd(const short* __restrict__ Qb,
                                                const short* __restrict__ Kb,
                                                const short* __restrict__ VTb,
                                                short* __restrict__ AO) {
  __shared__ __align__(16) float Os[4][16][68];   // [wave][q][d] (+4 pad)
  __shared__ float Ms[4][16];
  __shared__ float Ls[4][16];
  int bh = blockIdx.y;
  int b = bh / NH, h = bh % NH;
  int qt = (int)gridDim.x - 1 - (int)blockIdx.x;   // heavy tiles dispatch first
  int qbase = qt * 16;
  int wv = threadIdx.x >> 6;
  int lane = threadIdx.x & 63;
  int quad = lane >> 4, l16 = lane & 15;
  const short* Qp = Qb + (size_t)bh * SEQ * HD;
  const short* Kp = Kb + (size_t)bh * SEQ * HD;
  const short* Vp = VTb + (size_t)bh * HD * SEQ;

  // Q fragment as B-operand of K.Q^T: lane holds Q[qbase+l16][quad*8..+7 (+32)]
  short8 bq0 = *reinterpret_cast<const short8*>(Qp + (qbase + l16) * HD + quad * 8);
  short8 bq1 = *reinterpret_cast<const short8*>(Qp + (qbase + l16) * HD + 32 + quad * 8);

  floatx4 o[4] = {};              // O^T 16-d tiles, C-layout, col=q=l16
  float m_run = -1e30f, l_run = 0.f;
  int n32 = (qbase + 16 + 31) >> 5;   // causal: kv <= qbase+15

  int hi = quad >> 1;
  int sb = (quad & 1) << 1;

  for (int kt = wv; kt < n32; kt += 4) {
    int kb = kt << 5;
    // K as A-operand: A[m=kv][k=d]
    const short* kp0 = Kp + (kb + l16) * HD + quad * 8;
    const short* kp1 = kp0 + 16 * HD;
    short8 ka00 = *reinterpret_cast<const short8*>(kp0);
    short8 ka01 = *reinterpret_cast<const short8*>(kp0 + 32);
    short8 ka10 = *reinterpret_cast<const short8*>(kp1);
    short8 ka11 = *reinterpret_cast<const short8*>(kp1 + 32);
    floatx4 st0 = {}, st1 = {};
    st0 = mfma_bf16(ka00, bq0, st0);
    st0 = mfma_bf16(ka01, bq1, st0);
    st1 = mfma_bf16(ka10, bq0, st1);
    st1 = mfma_bf16(ka11, bq1, st1);
    // causal mask (only the final kv-tile can cross the diagonal)
    if (kt == n32 - 1) {
      int q = qbase + l16;
      #pragma unroll
      for (int r = 0; r < 4; ++r) {
        if (kb + quad * 4 + r > q)      st0[r] = -1e30f;
        if (kb + 16 + quad * 4 + r > q) st1[r] = -1e30f;
      }
    }
    // online softmax over column q = l16 (reduce across the 4 quads)
    float mloc = fmaxf(fmaxf(fmaxf(st0[0], st0[1]), fmaxf(st0[2], st0[3])),
                       fmaxf(fmaxf(st1[0], st1[1]), fmaxf(st1[2], st1[3])));
    mloc = fmaxf(mloc, __shfl_xor(mloc, 16));
    mloc = fmaxf(mloc, __shfl_xor(mloc, 32));
    float m_new = fmaxf(m_run, mloc);
    float p0[4], p1[4];
    float sloc = 0.f;
    #pragma unroll
    for (int r = 0; r < 4; ++r) { p0[r] = __expf(st0[r] - m_new); sloc += p0[r]; }
    #pragma unroll
    for (int r = 0; r < 4; ++r) { p1[r] = __expf(st1[r] - m_new); sloc += p1[r]; }
    sloc += __shfl_xor(sloc, 16);
    sloc += __shfl_xor(sloc, 32);
    float alpha = __expf(m_run - m_new);
    l_run = l_run * alpha + sloc;
    m_run = m_new;
    #pragma unroll
    for (int t = 0; t < 4; ++t) o[t] *= alpha;
    // remap P^T (C-layout, kv=quad*4+r per 16-tile) -> B-operand K=32 (kv=quad*8+j)
    // packed: both 16-tiles' bf16 in one 32-bit word -> one shfl moves both
    int pk[4];
    #pragma unroll
    for (int r = 0; r < 4; ++r)
      pk[r] = (int)(unsigned short)f2bf(p0[r]) | ((int)(unsigned short)f2bf(p1[r]) << 16);
    short8 pb;
    #pragma unroll
    for (int j = 0; j < 8; ++j) {
      int srcl = ((sb + (j >> 2)) << 4) + l16;
      int w = __shfl(pk[j & 3], srcl);
      pb[j] = (short)(hi ? (w >> 16) : (w & 0xffff));
    }
    // O^T += V^T . P^T : A[m=d][k=kv] from V^T (d-contiguous rows of length SEQ)
    const short* vp = Vp + l16 * SEQ + kb + quad * 8;
    #pragma unroll
    for (int t = 0; t < 4; ++t) {
      short8 va = *reinterpret_cast<const short8*>(vp + t * 16 * SEQ);
      o[t] = mfma_bf16(va, pb, o[t]);
    }
  }
  // ---- write partials to LDS ----
  #pragma unroll
  for (int t = 0; t < 4; ++t)
    *reinterpret_cast<floatx4*>(&Os[wv][l16][t * 16 + quad * 4]) = o[t];
  if (quad == 0) { Ms[wv][l16] = m_run; Ls[wv][l16] = l_run; }
  __syncthreads();
  // ---- merge: each wave finalizes 16 of the 64 d-dims ----
  float m0w = Ms[0][l16], m1w = Ms[1][l16], m2w = Ms[2][l16], m3w = Ms[3][l16];
  float M = fmaxf(fmaxf(m0w, m1w), fmaxf(m2w, m3w));
  float e0 = __expf(m0w - M), e1 = __expf(m1w - M),
        e2 = __expf(m2w - M), e3 = __expf(m3w - M);
  float ltot = Ls[0][l16] * e0 + Ls[1][l16] * e1 + Ls[2][l16] * e2 + Ls[3][l16] * e3;
  float inv = 1.f / ltot;
  int dloc = wv * 16 + quad * 4;
  floatx4 f0 = *reinterpret_cast<const floatx4*>(&Os[0][l16][dloc]);
  floatx4 f1 = *reinterpret_cast<const floatx4*>(&Os[1][l16][dloc]);
  floatx4 f2 = *reinterpret_cast<const floatx4*>(&Os[2][l16][dloc]);
  floatx4 f3 = *reinterpret_cast<const floatx4*>(&Os[3][l16][dloc]);
  int s = qbase + l16;
  size_t outbase = ((size_t)(b * SEQ + s)) * HIDDEN + h * HD + dloc;
  #pragma unroll
  for (int r = 0; r < 4; ++r) {
    float val = f0[r] * e0 + f1[r] * e1 + f2[r] * e2 + f3[r] * e3;
    AO[outbase + r] = f2bf(val * inv);
  }
}

// ---------------- GEMM2: out = AO @ W_out + b_out (fp32 out) ----------------
// Grid (32, 6), 256 threads.
__global__ __launch_bounds__(256) void gemm_out(const short* __restrict__ AO,
                                                const short* __restrict__ WT,
                                                const float* __restrict__ bias,
                                                float* __restrict__ out) {
  __shared__ short As[128 * LDT];
  __shared__ short Bs[128 * LDT];
  int m0 = blockIdx.x * 128, n0 = blockIdx.y * 128;
  int tid = threadIdx.x;
  int lane = tid & 63, wv = tid >> 6;
  int wm = (wv >> 1) << 6, wn = (wv & 1) << 6;
  int quad = lane >> 4, l16 = lane & 15;
  floatx4 acc[4][4] = {};
  for (int kk = 0; kk < HIDDEN; kk += 32) {
    __syncthreads();
    #pragma unroll
    for (int c = 0; c < 2; ++c) {
      int idx = (tid + c * 256) * 8;
      int r = idx >> 5, col = idx & 31;
      *reinterpret_cast<short8*>(&As[r * LDT + col]) =
          *reinterpret_cast<const short8*>(AO + (size_t)(m0 + r) * HIDDEN + kk + col);
      *reinterpret_cast<short8*>(&Bs[r * LDT + col]) =
          *reinterpret_cast<const short8*>(WT + (size_t)(n0 + r) * HIDDEN + kk + col);
    }
    __syncthreads();
    short8 af[4], bfr[4];
    #pragma unroll
    for (int i = 0; i < 4; ++i)
      af[i] = *reinterpret_cast<const short8*>(&As[(wm + i * 16 + l16) * LDT + quad * 8]);
    #pragma unroll
    for (int j = 0; j < 4; ++j)
      bfr[j] = *reinterpret_cast<const short8*>(&Bs[(wn + j * 16 + l16) * LDT + quad * 8]);
    #pragma unroll
    for (int i = 0; i < 4; ++i)
      #pragma unroll
      for (int j = 0; j < 4; ++j)
        acc[i][j] = mfma_bf16(af[i], bfr[j], acc[i][j]);
  }
  #pragma unroll
  for (int j = 0; j < 4; ++j) {
    int col = n0 + wn + j * 16 + l16;
    float bs = bias[col];
    #pragma unroll
    for (int i = 0; i < 4; ++i) {
      #pragma unroll
      for (int r = 0; r < 4; ++r) {
        int row = m0 + wm + i * 16 + quad * 4 + r;
        out[(size_t)row * HIDDEN + col] = acc[i][j][r] + bs;
      }
    }
  }
}

extern "C" void kernel_launch(void* const* d_in, const int* in_sizes, int n_in,
                              void* d_out, int out_size, void* d_ws, size_t ws_size,
                              hipStream_t stream) {
  const float* x    = (const float*)d_in[0];   // [2,2048,768]
  const float* Wqkv = (const float*)d_in[1];   // [768,2304]
  const float* bqkv = (const float*)d_in[2];   // [2304]
  const float* Wout = (const float*)d_in[3];   // [768,768]
  const float* bout = (const float*)d_in[4];   // [768]
  float* out = (float*)d_out;

  short* WqkvT = (short*)d_ws;                     // [2304][768] bf16
  short* WoutT = WqkvT + (size_t)NQKV * HIDDEN;    // [768][768]
  short* Qb    = WoutT + (size_t)HIDDEN * HIDDEN;  // [24][2048][64] (pre-scaled by 1/8)
  short* Kb    = Qb + (size_t)BHN * SEQ * HD;      // [24][2048][64]
  short* VTb   = Kb + (size_t)BHN * SEQ * HD;      // [24][64][2048]
  short* AO    = VTb + (size_t)BHN * SEQ * HD;     // [4096][768]
  // total ws used: ~29.9 MB

  transpose_cvt<<<dim3(NQKV / 64, HIDDEN / 64), 256, 0, stream>>>(Wqkv, WqkvT, HIDDEN, NQKV);
  transpose_cvt<<<dim3(HIDDEN / 64, HIDDEN / 64), 256, 0, stream>>>(Wout, WoutT, HIDDEN, HIDDEN);
  gemm_qkv<<<dim3(MTOT / 128, NQKV / 128), 256, 0, stream>>>(x, WqkvT, bqkv, Qb, Kb, VTb);
  attn_fwd<<<dim3(SEQ / 16, BHN), 256, 0, stream>>>(Qb, Kb, VTb, AO);
  gemm_out<<<dim3(MTOT / 128, HIDDEN / 128), 256, 0, stream>>>(AO, WoutT, bout, out);
}

// Round 3
// 248.246 us; speedup vs baseline: 1.2124x; 1.0535x over previous
//
#include <hip/hip_runtime.h>

typedef __attribute__((ext_vector_type(8))) short short8;
typedef __attribute__((ext_vector_type(4))) float floatx4;

#define HIDDEN 768
#define NH 12
#define HD 64
#define SEQ 2048
#define BATCH 2
#define BHN (BATCH*NH)      // 24
#define MTOT (BATCH*SEQ)    // 4096
#define NQKV (3*HIDDEN)     // 2304
#define LDT 40              // BK(32) + 8 pad, keeps 16B alignment (80B row stride)

__device__ __forceinline__ short f2bf(float f) {
  union { float f; unsigned u; } v; v.f = f;
  unsigned r = v.u + 0x7FFFu + ((v.u >> 16) & 1u);   // RNE
  return (short)(r >> 16);
}

__device__ __forceinline__ floatx4 mfma_bf16(short8 a, short8 b, floatx4 c) {
  return __builtin_amdgcn_mfma_f32_16x16x32_bf16(a, b, c, 0, 0, 0);
}

__device__ __forceinline__ short8 ld8(const short* p) {
  return *reinterpret_cast<const short8*>(p);
}

// ---------------- weight transpose + fp32->bf16 ----------------
// W [K][N] fp32  ->  WT [N][K] bf16.  Grid: (N/64, K/64), 256 threads.
__global__ __launch_bounds__(256) void transpose_cvt(const float* __restrict__ W,
                                                     short* __restrict__ WT,
                                                     int K, int N) {
  __shared__ short t[64][72];
  int nb = blockIdx.x * 64, kb = blockIdx.y * 64;
  int tid = threadIdx.x;
  {
    int k  = tid >> 2;
    int n0 = (tid & 3) << 4;
    const float4* src = reinterpret_cast<const float4*>(W + (size_t)(kb + k) * N + nb + n0);
    #pragma unroll
    for (int c = 0; c < 4; ++c) {
      float4 v = src[c];
      t[n0 + c*4 + 0][k] = f2bf(v.x);
      t[n0 + c*4 + 1][k] = f2bf(v.y);
      t[n0 + c*4 + 2][k] = f2bf(v.z);
      t[n0 + c*4 + 3][k] = f2bf(v.w);
    }
  }
  __syncthreads();
  {
    int n  = tid >> 2;
    int k0 = (tid & 3) << 4;
    const short8* row = reinterpret_cast<const short8*>(&t[n][k0]);
    short8* dst = reinterpret_cast<short8*>(WT + (size_t)(nb + n) * K + kb + k0);
    dst[0] = row[0];
    dst[1] = row[1];
  }
}

// ---------------- X fp32 -> bf16 (streaming) ----------------
__global__ __launch_bounds__(256) void cvt_x(const float* __restrict__ X,
                                             short* __restrict__ Xb) {
  int i = (blockIdx.x * 256 + threadIdx.x) * 8;
  const float4* s = reinterpret_cast<const float4*>(X + i);
  float4 v0 = s[0], v1 = s[1];
  short8 o;
  o[0] = f2bf(v0.x); o[1] = f2bf(v0.y); o[2] = f2bf(v0.z); o[3] = f2bf(v0.w);
  o[4] = f2bf(v1.x); o[5] = f2bf(v1.y); o[6] = f2bf(v1.z); o[7] = f2bf(v1.w);
  *reinterpret_cast<short8*>(Xb + i) = o;
}

// ---------------- GEMM1: qkv = Xb @ W_qkv + b, scatter to Q(,/8)/K/V^T bf16 ----------------
// Grid (4096/128, 2304/128) = (32,18), 256 threads = 4 waves (2x2 of 64x64).
__global__ __launch_bounds__(256) void gemm_qkv(const short* __restrict__ Xb,
                                                const short* __restrict__ WT,
                                                const float* __restrict__ bias,
                                                short* __restrict__ Qb,
                                                short* __restrict__ Kb,
                                                short* __restrict__ VTb) {
  __shared__ short As[128 * LDT];
  __shared__ short Bs[128 * LDT];
  int m0 = blockIdx.x * 128, n0 = blockIdx.y * 128;
  int tid = threadIdx.x;
  int lane = tid & 63, wv = tid >> 6;
  int wm = (wv >> 1) << 6, wn = (wv & 1) << 6;
  int quad = lane >> 4, l16 = lane & 15;
  floatx4 acc[4][4] = {};
  for (int kk = 0; kk < HIDDEN; kk += 32) {
    __syncthreads();
    #pragma unroll
    for (int c = 0; c < 2; ++c) {
      int idx = (tid + c * 256) * 8;
      int r = idx >> 5, col = idx & 31;
      *reinterpret_cast<short8*>(&As[r * LDT + col]) =
          ld8(Xb + (size_t)(m0 + r) * HIDDEN + kk + col);
      *reinterpret_cast<short8*>(&Bs[r * LDT + col]) =
          ld8(WT + (size_t)(n0 + r) * HIDDEN + kk + col);
    }
    __syncthreads();
    short8 af[4], bfr[4];
    #pragma unroll
    for (int i = 0; i < 4; ++i)
      af[i] = *reinterpret_cast<const short8*>(&As[(wm + i * 16 + l16) * LDT + quad * 8]);
    #pragma unroll
    for (int j = 0; j < 4; ++j)
      bfr[j] = *reinterpret_cast<const short8*>(&Bs[(wn + j * 16 + l16) * LDT + quad * 8]);
    #pragma unroll
    for (int i = 0; i < 4; ++i)
      #pragma unroll
      for (int j = 0; j < 4; ++j)
        acc[i][j] = mfma_bf16(af[i], bfr[j], acc[i][j]);
  }
  // epilogue: bias, split into Q (scaled 1/8), K, V^T
  int colbase = n0 + wn;
  int part = colbase / HIDDEN;   // uniform per wave (128 | 768)
  #pragma unroll
  for (int j = 0; j < 4; ++j) {
    int col = colbase + j * 16 + l16;
    float bs = bias[col];
    int rem = col - part * HIDDEN;
    int h = rem >> 6, d = rem & 63;
    #pragma unroll
    for (int i = 0; i < 4; ++i) {
      #pragma unroll
      for (int r = 0; r < 4; ++r) {
        int row = m0 + wm + i * 16 + quad * 4 + r;
        float v = acc[i][j][r] + bs;
        int bb = row >> 11, s = row & 2047;
        int bh = bb * NH + h;
        if (part == 0) {
          Qb[((size_t)bh * SEQ + s) * HD + d] = f2bf(v * 0.125f);   // fold 1/sqrt(64)
        } else if (part == 1) {
          Kb[((size_t)bh * SEQ + s) * HD + d] = f2bf(v);
        } else {
          VTb[((size_t)bh * HD + d) * SEQ + s] = f2bf(v);
        }
      }
    }
  }
}

// ---------------- flash attention, causal, split-kv within block ----------------
// One block per 16-row Q-tile. 4 waves process interleaved 32-kv tiles with
// private online-softmax state, merged via LDS. XCD-affine 1-D grid: class
// blk&7 -> one XCD serves 3 heads (1.5 MB K/V fits its 4 MB L2), heavy q first.
// Explicit K/V register pipeline: next tile's loads issue before the softmax
// chain. __launch_bounds__(256,4): 128-VGPR budget, 4 waves/SIMD.
__global__ __launch_bounds__(256, 4) void attn_fwd(const short* __restrict__ Qb,
                                                   const short* __restrict__ Kb,
                                                   const short* __restrict__ VTb,
                                                   short* __restrict__ AO) {
  __shared__ __align__(16) float Os[4][16][68];
  __shared__ float Ms[4][16];
  __shared__ float Ls[4][16];
  int blk = blockIdx.x;
  int cls = blk & 7;          // XCD class (dispatch round-robin heuristic)
  int j   = blk >> 3;         // 0..383 within class
  int bh  = cls + 8 * (j >> 7);   // 3 heads per class
  int qt  = 127 - (j & 127);      // heavy tiles first within class
  int qbase = qt * 16;
  int wv = threadIdx.x >> 6;
  int lane = threadIdx.x & 63;
  int quad = lane >> 4, l16 = lane & 15;
  int b = bh / NH, h = bh % NH;
  const short* Qp = Qb + (size_t)bh * SEQ * HD;
  const short* Kp = Kb + (size_t)bh * SEQ * HD;
  const short* Vp = VTb + (size_t)bh * HD * SEQ;

  // Q fragment as B-operand of K.Q^T: lane holds Q[qbase+l16][quad*8..+7 (+32)]
  short8 bq0 = ld8(Qp + (qbase + l16) * HD + quad * 8);
  short8 bq1 = ld8(Qp + (qbase + l16) * HD + 32 + quad * 8);

  floatx4 o[4] = {};              // O^T 16-d tiles, C-layout, col=q=l16
  float m_run = -1e30f, l_run = 0.f;
  int n32 = (qbase + 16 + 31) >> 5;   // causal: kv <= qbase+15

  int hi = quad >> 1;
  int sb = (quad & 1) << 1;

  short8 ka[4], va[4];
  int kt = wv;
  if (kt < n32) {
    int kb = kt << 5;
    const short* kp = Kp + (kb + l16) * HD + quad * 8;
    ka[0] = ld8(kp);           ka[1] = ld8(kp + 32);
    ka[2] = ld8(kp + 16 * HD); ka[3] = ld8(kp + 16 * HD + 32);
    const short* vp = Vp + l16 * SEQ + kb + quad * 8;
    va[0] = ld8(vp);            va[1] = ld8(vp + 16 * SEQ);
    va[2] = ld8(vp + 32 * SEQ); va[3] = ld8(vp + 48 * SEQ);
  }

  for (; kt < n32; kt += 4) {
    int kb = kt << 5;
    floatx4 st0 = {}, st1 = {};
    st0 = mfma_bf16(ka[0], bq0, st0);
    st0 = mfma_bf16(ka[1], bq1, st0);
    st1 = mfma_bf16(ka[2], bq0, st1);
    st1 = mfma_bf16(ka[3], bq1, st1);

    // prefetch next tile NOW — overlaps the softmax chain below
    short8 kan[4], van[4];
    int ktn = kt + 4;
    if (ktn < n32) {
      int kbn = ktn << 5;
      const short* kp = Kp + (kbn + l16) * HD + quad * 8;
      kan[0] = ld8(kp);           kan[1] = ld8(kp + 32);
      kan[2] = ld8(kp + 16 * HD); kan[3] = ld8(kp + 16 * HD + 32);
      const short* vp = Vp + l16 * SEQ + kbn + quad * 8;
      van[0] = ld8(vp);            van[1] = ld8(vp + 16 * SEQ);
      van[2] = ld8(vp + 32 * SEQ); van[3] = ld8(vp + 48 * SEQ);
    }

    // causal mask (only the final kv-tile can cross the diagonal)
    if (kt == n32 - 1) {
      int q = qbase + l16;
      #pragma unroll
      for (int r = 0; r < 4; ++r) {
        if (kb + quad * 4 + r > q)      st0[r] = -1e30f;
        if (kb + 16 + quad * 4 + r > q) st1[r] = -1e30f;
      }
    }
    // online softmax over column q = l16 (reduce across the 4 quads)
    float mloc = fmaxf(fmaxf(fmaxf(st0[0], st0[1]), fmaxf(st0[2], st0[3])),
                       fmaxf(fmaxf(st1[0], st1[1]), fmaxf(st1[2], st1[3])));
    mloc = fmaxf(mloc, __shfl_xor(mloc, 16));
    mloc = fmaxf(mloc, __shfl_xor(mloc, 32));
    float m_new = fmaxf(m_run, mloc);
    float p0[4], p1[4];
    float sloc = 0.f;
    #pragma unroll
    for (int r = 0; r < 4; ++r) { p0[r] = __expf(st0[r] - m_new); sloc += p0[r]; }
    #pragma unroll
    for (int r = 0; r < 4; ++r) { p1[r] = __expf(st1[r] - m_new); sloc += p1[r]; }
    sloc += __shfl_xor(sloc, 16);
    sloc += __shfl_xor(sloc, 32);
    float alpha = __expf(m_run - m_new);
    l_run = l_run * alpha + sloc;
    m_run = m_new;
    #pragma unroll
    for (int t = 0; t < 4; ++t) o[t] *= alpha;
    // remap P^T (C-layout, kv=quad*4+r per 16-tile) -> B-operand K=32 (kv=quad*8+j)
    int pk[4];
    #pragma unroll
    for (int r = 0; r < 4; ++r)
      pk[r] = (int)(unsigned short)f2bf(p0[r]) | ((int)(unsigned short)f2bf(p1[r]) << 16);
    short8 pb;
    #pragma unroll
    for (int jj = 0; jj < 8; ++jj) {
      int srcl = ((sb + (jj >> 2)) << 4) + l16;
      int w = __shfl(pk[jj & 3], srcl);
      pb[jj] = (short)(hi ? (w >> 16) : (w & 0xffff));
    }
    // O^T += V^T . P^T
    #pragma unroll
    for (int t = 0; t < 4; ++t)
      o[t] = mfma_bf16(va[t], pb, o[t]);
    #pragma unroll
    for (int t = 0; t < 4; ++t) { ka[t] = kan[t]; va[t] = van[t]; }
  }
  // ---- write partials to LDS ----
  #pragma unroll
  for (int t = 0; t < 4; ++t)
    *reinterpret_cast<floatx4*>(&Os[wv][l16][t * 16 + quad * 4]) = o[t];
  if (quad == 0) { Ms[wv][l16] = m_run; Ls[wv][l16] = l_run; }
  __syncthreads();
  // ---- merge: each wave finalizes 16 of the 64 d-dims ----
  float m0w = Ms[0][l16], m1w = Ms[1][l16], m2w = Ms[2][l16], m3w = Ms[3][l16];
  float M = fmaxf(fmaxf(m0w, m1w), fmaxf(m2w, m3w));
  float e0 = __expf(m0w - M), e1 = __expf(m1w - M),
        e2 = __expf(m2w - M), e3 = __expf(m3w - M);
  float ltot = Ls[0][l16] * e0 + Ls[1][l16] * e1 + Ls[2][l16] * e2 + Ls[3][l16] * e3;
  float inv = 1.f / ltot;
  int dloc = wv * 16 + quad * 4;
  floatx4 f0 = *reinterpret_cast<const floatx4*>(&Os[0][l16][dloc]);
  floatx4 f1 = *reinterpret_cast<const floatx4*>(&Os[1][l16][dloc]);
  floatx4 f2 = *reinterpret_cast<const floatx4*>(&Os[2][l16][dloc]);
  floatx4 f3 = *reinterpret_cast<const floatx4*>(&Os[3][l16][dloc]);
  int s = qbase + l16;
  size_t outbase = ((size_t)(b * SEQ + s)) * HIDDEN + h * HD + dloc;
  #pragma unroll
  for (int r = 0; r < 4; ++r) {
    float val = f0[r] * e0 + f1[r] * e1 + f2[r] * e2 + f3[r] * e3;
    AO[outbase + r] = f2bf(val * inv);
  }
}

// ---------------- GEMM2: out = AO @ W_out + b_out (fp32 out) ----------------
// Grid (32, 6), 256 threads.
__global__ __launch_bounds__(256) void gemm_out(const short* __restrict__ AO,
                                                const short* __restrict__ WT,
                                                const float* __restrict__ bias,
                                                float* __restrict__ out) {
  __shared__ short As[128 * LDT];
  __shared__ short Bs[128 * LDT];
  int m0 = blockIdx.x * 128, n0 = blockIdx.y * 128;
  int tid = threadIdx.x;
  int lane = tid & 63, wv = tid >> 6;
  int wm = (wv >> 1) << 6, wn = (wv & 1) << 6;
  int quad = lane >> 4, l16 = lane & 15;
  floatx4 acc[4][4] = {};
  for (int kk = 0; kk < HIDDEN; kk += 32) {
    __syncthreads();
    #pragma unroll
    for (int c = 0; c < 2; ++c) {
      int idx = (tid + c * 256) * 8;
      int r = idx >> 5, col = idx & 31;
      *reinterpret_cast<short8*>(&As[r * LDT + col]) =
          ld8(AO + (size_t)(m0 + r) * HIDDEN + kk + col);
      *reinterpret_cast<short8*>(&Bs[r * LDT + col]) =
          ld8(WT + (size_t)(n0 + r) * HIDDEN + kk + col);
    }
    __syncthreads();
    short8 af[4], bfr[4];
    #pragma unroll
    for (int i = 0; i < 4; ++i)
      af[i] = *reinterpret_cast<const short8*>(&As[(wm + i * 16 + l16) * LDT + quad * 8]);
    #pragma unroll
    for (int j = 0; j < 4; ++j)
      bfr[j] = *reinterpret_cast<const short8*>(&Bs[(wn + j * 16 + l16) * LDT + quad * 8]);
    #pragma unroll
    for (int i = 0; i < 4; ++i)
      #pragma unroll
      for (int j = 0; j < 4; ++j)
        acc[i][j] = mfma_bf16(af[i], bfr[j], acc[i][j]);
  }
  #pragma unroll
  for (int j = 0; j < 4; ++j) {
    int col = n0 + wn + j * 16 + l16;
    float bs = bias[col];
    #pragma unroll
    for (int i = 0; i < 4; ++i) {
      #pragma unroll
      for (int r = 0; r < 4; ++r) {
        int row = m0 + wm + i * 16 + quad * 4 + r;
        out[(size_t)row * HIDDEN + col] = acc[i][j][r] + bs;
      }
    }
  }
}

extern "C" void kernel_launch(void* const* d_in, const int* in_sizes, int n_in,
                              void* d_out, int out_size, void* d_ws, size_t ws_size,
                              hipStream_t stream) {
  const float* x    = (const float*)d_in[0];   // [2,2048,768]
  const float* Wqkv = (const float*)d_in[1];   // [768,2304]
  const float* bqkv = (const float*)d_in[2];   // [2304]
  const float* Wout = (const float*)d_in[3];   // [768,768]
  const float* bout = (const float*)d_in[4];   // [768]
  float* out = (float*)d_out;

  short* WqkvT = (short*)d_ws;                     // [2304][768] bf16
  short* WoutT = WqkvT + (size_t)NQKV * HIDDEN;    // [768][768]
  short* Qb    = WoutT + (size_t)HIDDEN * HIDDEN;  // [24][2048][64] (pre-scaled by 1/8)
  short* Kb    = Qb + (size_t)BHN * SEQ * HD;      // [24][2048][64]
  short* VTb   = Kb + (size_t)BHN * SEQ * HD;      // [24][64][2048]
  short* AO    = VTb + (size_t)BHN * SEQ * HD;     // [4096][768]
  short* Xb    = AO + (size_t)MTOT * HIDDEN;       // [4096][768]
  // total ws used: ~36 MB

  cvt_x<<<dim3(MTOT * HIDDEN / (256 * 8)), 256, 0, stream>>>(x, Xb);
  transpose_cvt<<<dim3(NQKV / 64, HIDDEN / 64), 256, 0, stream>>>(Wqkv, WqkvT, HIDDEN, NQKV);
  transpose_cvt<<<dim3(HIDDEN / 64, HIDDEN / 64), 256, 0, stream>>>(Wout, WoutT, HIDDEN, HIDDEN);
  gemm_qkv<<<dim3(MTOT / 128, NQKV / 128), 256, 0, stream>>>(Xb, WqkvT, bqkv, Qb, Kb, VTb);
  attn_fwd<<<dim3(SEQ / 16 * BHN), 256, 0, stream>>>(Qb, Kb, VTb, AO);
  gemm_out<<<dim3(MTOT / 128, HIDDEN / 128), 256, 0, stream>>>(AO, WoutT, bout, out);
}

// Round 4
// 205.724 us; speedup vs baseline: 1.4630x; 1.2067x over previous
//
#include <hip/hip_runtime.h>

typedef __attribute__((ext_vector_type(8))) short short8;
typedef __attribute__((ext_vector_type(4))) short short4v;
typedef __attribute__((ext_vector_type(4))) float floatx4;
typedef __attribute__((ext_vector_type(16))) float floatx16;

#define HIDDEN 768
#define NH 12
#define HD 64
#define SEQ 2048
#define BATCH 2
#define BHN (BATCH*NH)      // 24
#define MTOT (BATCH*SEQ)    // 4096
#define NQKV (3*HIDDEN)     // 2304
#define LDT 40              // BK(32) + 8 pad for the GEMM kernels

__device__ __forceinline__ short f2bf(float f) {
  union { float f; unsigned u; } v; v.f = f;
  unsigned r = v.u + 0x7FFFu + ((v.u >> 16) & 1u);   // RNE
  return (short)(r >> 16);
}
__device__ __forceinline__ unsigned pk2(float a, float b) {
  return (unsigned)(unsigned short)f2bf(a) | ((unsigned)(unsigned short)f2bf(b) << 16);
}
__device__ __forceinline__ floatx4 mfma_bf16(short8 a, short8 b, floatx4 c) {
  return __builtin_amdgcn_mfma_f32_16x16x32_bf16(a, b, c, 0, 0, 0);
}
__device__ __forceinline__ floatx16 mfma32(short8 a, short8 b, floatx16 c) {
  return __builtin_amdgcn_mfma_f32_32x32x16_bf16(a, b, c, 0, 0, 0);
}
__device__ __forceinline__ short8 ld8(const short* p) {
  return *reinterpret_cast<const short8*>(p);
}

// ---------------- weight transpose + fp32->bf16 ----------------
__global__ __launch_bounds__(256) void transpose_cvt(const float* __restrict__ W,
                                                     short* __restrict__ WT,
                                                     int K, int N) {
  __shared__ short t[64][72];
  int nb = blockIdx.x * 64, kb = blockIdx.y * 64;
  int tid = threadIdx.x;
  {
    int k  = tid >> 2;
    int n0 = (tid & 3) << 4;
    const float4* src = reinterpret_cast<const float4*>(W + (size_t)(kb + k) * N + nb + n0);
    #pragma unroll
    for (int c = 0; c < 4; ++c) {
      float4 v = src[c];
      t[n0 + c*4 + 0][k] = f2bf(v.x);
      t[n0 + c*4 + 1][k] = f2bf(v.y);
      t[n0 + c*4 + 2][k] = f2bf(v.z);
      t[n0 + c*4 + 3][k] = f2bf(v.w);
    }
  }
  __syncthreads();
  {
    int n  = tid >> 2;
    int k0 = (tid & 3) << 4;
    const short8* row = reinterpret_cast<const short8*>(&t[n][k0]);
    short8* dst = reinterpret_cast<short8*>(WT + (size_t)(nb + n) * K + kb + k0);
    dst[0] = row[0];
    dst[1] = row[1];
  }
}

// ---------------- X fp32 -> bf16 ----------------
__global__ __launch_bounds__(256) void cvt_x(const float* __restrict__ X,
                                             short* __restrict__ Xb) {
  int i = (blockIdx.x * 256 + threadIdx.x) * 8;
  const float4* s = reinterpret_cast<const float4*>(X + i);
  float4 v0 = s[0], v1 = s[1];
  short8 o;
  o[0] = f2bf(v0.x); o[1] = f2bf(v0.y); o[2] = f2bf(v0.z); o[3] = f2bf(v0.w);
  o[4] = f2bf(v1.x); o[5] = f2bf(v1.y); o[6] = f2bf(v1.z); o[7] = f2bf(v1.w);
  *reinterpret_cast<short8*>(Xb + i) = o;
}

// ---------------- GEMM1 ----------------
__global__ __launch_bounds__(256) void gemm_qkv(const short* __restrict__ Xb,
                                                const short* __restrict__ WT,
                                                const float* __restrict__ bias,
                                                short* __restrict__ Qb,
                                                short* __restrict__ Kb,
                                                short* __restrict__ VTb) {
  __shared__ short As[128 * LDT];
  __shared__ short Bs[128 * LDT];
  int m0 = blockIdx.x * 128, n0 = blockIdx.y * 128;
  int tid = threadIdx.x;
  int lane = tid & 63, wv = tid >> 6;
  int wm = (wv >> 1) << 6, wn = (wv & 1) << 6;
  int quad = lane >> 4, l16 = lane & 15;
  floatx4 acc[4][4] = {};
  for (int kk = 0; kk < HIDDEN; kk += 32) {
    __syncthreads();
    #pragma unroll
    for (int c = 0; c < 2; ++c) {
      int idx = (tid + c * 256) * 8;
      int r = idx >> 5, col = idx & 31;
      *reinterpret_cast<short8*>(&As[r * LDT + col]) =
          ld8(Xb + (size_t)(m0 + r) * HIDDEN + kk + col);
      *reinterpret_cast<short8*>(&Bs[r * LDT + col]) =
          ld8(WT + (size_t)(n0 + r) * HIDDEN + kk + col);
    }
    __syncthreads();
    short8 af[4], bfr[4];
    #pragma unroll
    for (int i = 0; i < 4; ++i)
      af[i] = *reinterpret_cast<const short8*>(&As[(wm + i * 16 + l16) * LDT + quad * 8]);
    #pragma unroll
    for (int j = 0; j < 4; ++j)
      bfr[j] = *reinterpret_cast<const short8*>(&Bs[(wn + j * 16 + l16) * LDT + quad * 8]);
    #pragma unroll
    for (int i = 0; i < 4; ++i)
      #pragma unroll
      for (int j = 0; j < 4; ++j)
        acc[i][j] = mfma_bf16(af[i], bfr[j], acc[i][j]);
  }
  int colbase = n0 + wn;
  int part = colbase / HIDDEN;
  #pragma unroll
  for (int j = 0; j < 4; ++j) {
    int col = colbase + j * 16 + l16;
    float bs = bias[col];
    int rem = col - part * HIDDEN;
    int h = rem >> 6, d = rem & 63;
    #pragma unroll
    for (int i = 0; i < 4; ++i) {
      #pragma unroll
      for (int r = 0; r < 4; ++r) {
        int row = m0 + wm + i * 16 + quad * 4 + r;
        float v = acc[i][j][r] + bs;
        int bb = row >> 11, s = row & 2047;
        int bh = bb * NH + h;
        if (part == 0) {
          Qb[((size_t)bh * SEQ + s) * HD + d] = f2bf(v * 0.125f);
        } else if (part == 1) {
          Kb[((size_t)bh * SEQ + s) * HD + d] = f2bf(v);
        } else {
          VTb[((size_t)bh * HD + d) * SEQ + s] = f2bf(v);
        }
      }
    }
  }
}

// ---------------- flash attention, causal, 32x32 MFMA + LDS double-buffer ----------------
// Block = (head, 128 q-rows): 4 waves x 32 q. kv loop over 64-kv tiles staged in
// LDS (K 8KB + V^T 8KB, ping-pong). XOR-swizzled 16B chunks: byte addr =
// row<<7 | ((chunk^ (row&7))<<4) -> conflict-minimal b128 reads AND writes.
// S^T = K.Q^T per 32-kv tile (C-layout col=q); softmax reduce = in-reg + one
// shfl_xor(32). P^T -> PV B-operand needs only the lane>>5 bit: 2 packed
// shfl_xor(32) per 16-kv chunk. O^T = V^T.P^T. Waves past their diagonal skip
// compute but keep staging+barriers.
__global__ __launch_bounds__(256, 4) void attn_fwd(const short* __restrict__ Qb,
                                                   const short* __restrict__ Kb,
                                                   const short* __restrict__ VTb,
                                                   short* __restrict__ AO) {
  __shared__ __align__(16) char lds[32768];   // K: buf*8192 ; V: 16384 + buf*8192
  int blk = blockIdx.x;
  int cls = blk & 7;                 // XCD class
  int j   = blk >> 3;                // 0..47
  int bh  = cls + 8 * (j >> 4);      // 3 heads per class
  int qblk = 15 - (j & 15);          // heavy first
  int qb0 = qblk * 128;
  int tid = threadIdx.x;
  int lane = tid & 63, wv = tid >> 6;
  int l31 = lane & 31, h = lane >> 5, x = lane & 7;
  int b = bh / NH, hh = bh % NH;
  const short* Qp = Qb + (size_t)bh * SEQ * HD;
  const short* Kp = Kb + (size_t)bh * SEQ * HD;
  const short* Vp = VTb + (size_t)bh * HD * SEQ;

  int qs  = qb0 + wv * 32 + l31;     // my q column
  int qlo = qb0 + wv * 32;
  int qhi = qlo + 31;
  int nt  = 2 * qblk + 2;            // number of 64-kv tiles

  // Q B-operand frags: B[k=d][n=q], d = dc*16 + h*8 + j
  short8 bq[4];
  #pragma unroll
  for (int dc = 0; dc < 4; ++dc)
    bq[dc] = ld8(Qp + qs * HD + dc * 16 + h * 8);

  // staging mapping: thread -> row sr, chunk-pair scg (2 x 16B)
  int sr = tid >> 2, scg = tid & 3;
  const short* kg = Kp + sr * HD + scg * 16;    // advances by 64*HD shorts/tile
  const short* vg = Vp + (size_t)sr * SEQ + scg * 16;  // advances by 64 shorts/tile
  int wbase = (sr << 7) | ((((scg << 1)) ^ (sr & 7)) << 4);

  // frag read vaddrs (per 16-kv/16-d chunk kc): row=l31, chunk=(kc*2+h)^x
  int rbase[4];
  #pragma unroll
  for (int kc = 0; kc < 4; ++kc)
    rbase[kc] = (l31 << 7) | (((((kc << 1) | h)) ^ x) << 4);

  // ---- prologue: stage tile 0 into buf 0 ----
  {
    short8 k0 = ld8(kg), k1 = ld8(kg + 8);
    short8 v0 = ld8(vg), v1 = ld8(vg + 8);
    *reinterpret_cast<short8*>(lds + wbase)            = k0;
    *reinterpret_cast<short8*>(lds + (wbase ^ 16))     = k1;
    *reinterpret_cast<short8*>(lds + 16384 + wbase)        = v0;
    *reinterpret_cast<short8*>(lds + 16384 + (wbase ^ 16)) = v1;
  }
  __syncthreads();

  floatx16 o0 = {}, o1 = {};
  float m_run = -1e30f, l_run = 0.f;

  for (int kt = 0; kt < nt; ++kt) {
    int cur = kt & 1;
    int curK = cur * 8192, curV = 16384 + cur * 8192;
    int kb = kt * 64;
    bool have_next = (kt + 1 < nt);

    // 1) issue next tile's global loads early
    short8 nk0, nk1, nv0, nv1;
    if (have_next) {
      kg += 64 * HD; vg += 64;
      nk0 = ld8(kg); nk1 = ld8(kg + 8);
      nv0 = ld8(vg); nv1 = ld8(vg + 8);
    }

    // 2) compute (wave-uniform skip past diagonal)
    if (kb <= qhi) {
      floatx16 s0 = {}, s1 = {};
      #pragma unroll
      for (int kc = 0; kc < 4; ++kc) {
        short8 ka0 = *reinterpret_cast<const short8*>(lds + curK + rbase[kc]);
        short8 ka1 = *reinterpret_cast<const short8*>(lds + curK + 4096 + rbase[kc]);
        s0 = mfma32(ka0, bq[kc], s0);
        s1 = mfma32(ka1, bq[kc], s1);
      }
      if (kb + 63 > qlo) {   // diagonal crossing: mask
        #pragma unroll
        for (int r = 0; r < 16; ++r) {
          int kvr = kb + (r & 3) + 8 * (r >> 2) + 4 * h;
          s0[r] = (kvr > qs) ? -1e30f : s0[r];
          s1[r] = (kvr + 32 > qs) ? -1e30f : s1[r];
        }
      }
      // online softmax over col q (in-register + one shfl_xor 32)
      float mloc = m_run;
      #pragma unroll
      for (int r = 0; r < 16; ++r) { mloc = fmaxf(mloc, s0[r]); mloc = fmaxf(mloc, s1[r]); }
      mloc = fmaxf(mloc, __shfl_xor(mloc, 32));
      float m_new = mloc;
      float alpha = __expf(m_run - m_new);
      float sloc = 0.f;
      #pragma unroll
      for (int r = 0; r < 16; ++r) {
        s0[r] = __expf(s0[r] - m_new); sloc += s0[r];
        s1[r] = __expf(s1[r] - m_new); sloc += s1[r];
      }
      sloc += __shfl_xor(sloc, 32);
      l_run = l_run * alpha + sloc;
      m_run = m_new;
      o0 *= alpha; o1 *= alpha;
      // remap P^T (C-layout) -> B-operand frags pb[kvc] via one lane-bit exchange
      short8 pb[4];
      #pragma unroll
      for (int kvc = 0; kvc < 4; ++kvc) {
        int base = (kvc & 1) * 8;
        const floatx16& P = (kvc < 2) ? s0 : s1;
        unsigned e0 = pk2(P[base + 0], P[base + 1]);
        unsigned e1 = pk2(P[base + 2], P[base + 3]);
        unsigned f0 = pk2(P[base + 4], P[base + 5]);
        unsigned f1 = pk2(P[base + 6], P[base + 7]);
        unsigned k_0 = h ? f0 : e0, k_1 = h ? f1 : e1;   // kept: regs base+4h+r
        unsigned s_0 = h ? e0 : f0, s_1 = h ? e1 : f1;   // sent: regs base+4(1-h)+r
        unsigned r_0 = __shfl_xor((int)s_0, 32);
        unsigned r_1 = __shfl_xor((int)s_1, 32);
        union { unsigned u[4]; short8 v; } pbu;
        pbu.u[0] = h ? r_0 : k_0;   // j=0..1  (from h_s=0 lane)
        pbu.u[1] = h ? r_1 : k_1;   // j=2..3
        pbu.u[2] = h ? k_0 : r_0;   // j=4..5  (from h_s=1 lane)
        pbu.u[3] = h ? k_1 : r_1;   // j=6..7
        pb[kvc] = pbu.v;
      }
      // O^T += V^T . P^T
      #pragma unroll
      for (int kvc = 0; kvc < 4; ++kvc) {
        short8 va0 = *reinterpret_cast<const short8*>(lds + curV + rbase[kvc]);
        short8 va1 = *reinterpret_cast<const short8*>(lds + curV + 4096 + rbase[kvc]);
        o0 = mfma32(va0, pb[kvc], o0);
        o1 = mfma32(va1, pb[kvc], o1);
      }
    }

    // 3) stage next tile into the other buffer
    if (have_next) {
      int nK = (cur ^ 1) * 8192, nV = 16384 + (cur ^ 1) * 8192;
      *reinterpret_cast<short8*>(lds + nK + wbase)        = nk0;
      *reinterpret_cast<short8*>(lds + nK + (wbase ^ 16)) = nk1;
      *reinterpret_cast<short8*>(lds + nV + wbase)        = nv0;
      *reinterpret_cast<short8*>(lds + nV + (wbase ^ 16)) = nv1;
    }
    __syncthreads();
  }

  // ---- epilogue: direct store (no merge; waves own disjoint q) ----
  float inv = 1.f / l_run;
  size_t obase = ((size_t)(b * SEQ + qs)) * HIDDEN + hh * HD;
  #pragma unroll
  for (int dt = 0; dt < 2; ++dt) {
    #pragma unroll
    for (int c = 0; c < 4; ++c) {
      int d = dt * 32 + 8 * c + 4 * h;
      short4v w;
      #pragma unroll
      for (int r = 0; r < 4; ++r) {
        float val = (dt ? o1[4 * c + r] : o0[4 * c + r]) * inv;
        w[r] = f2bf(val);
      }
      *reinterpret_cast<short4v*>(AO + obase + d) = w;
    }
  }
}

// ---------------- GEMM2 ----------------
__global__ __launch_bounds__(256) void gemm_out(const short* __restrict__ AO,
                                                const short* __restrict__ WT,
                                                const float* __restrict__ bias,
                                                float* __restrict__ out) {
  __shared__ short As[128 * LDT];
  __shared__ short Bs[128 * LDT];
  int m0 = blockIdx.x * 128, n0 = blockIdx.y * 128;
  int tid = threadIdx.x;
  int lane = tid & 63, wv = tid >> 6;
  int wm = (wv >> 1) << 6, wn = (wv & 1) << 6;
  int quad = lane >> 4, l16 = lane & 15;
  floatx4 acc[4][4] = {};
  for (int kk = 0; kk < HIDDEN; kk += 32) {
    __syncthreads();
    #pragma unroll
    for (int c = 0; c < 2; ++c) {
      int idx = (tid + c * 256) * 8;
      int r = idx >> 5, col = idx & 31;
      *reinterpret_cast<short8*>(&As[r * LDT + col]) =
          ld8(AO + (size_t)(m0 + r) * HIDDEN + kk + col);
      *reinterpret_cast<short8*>(&Bs[r * LDT + col]) =
          ld8(WT + (size_t)(n0 + r) * HIDDEN + kk + col);
    }
    __syncthreads();
    short8 af[4], bfr[4];
    #pragma unroll
    for (int i = 0; i < 4; ++i)
      af[i] = *reinterpret_cast<const short8*>(&As[(wm + i * 16 + l16) * LDT + quad * 8]);
    #pragma unroll
    for (int j = 0; j < 4; ++j)
      bfr[j] = *reinterpret_cast<const short8*>(&Bs[(wn + j * 16 + l16) * LDT + quad * 8]);
    #pragma unroll
    for (int i = 0; i < 4; ++i)
      #pragma unroll
      for (int j = 0; j < 4; ++j)
        acc[i][j] = mfma_bf16(af[i], bfr[j], acc[i][j]);
  }
  #pragma unroll
  for (int j = 0; j < 4; ++j) {
    int col = n0 + wn + j * 16 + l16;
    float bs = bias[col];
    #pragma unroll
    for (int i = 0; i < 4; ++i) {
      #pragma unroll
      for (int r = 0; r < 4; ++r) {
        int row = m0 + wm + i * 16 + quad * 4 + r;
        out[(size_t)row * HIDDEN + col] = acc[i][j][r] + bs;
      }
    }
  }
}

extern "C" void kernel_launch(void* const* d_in, const int* in_sizes, int n_in,
                              void* d_out, int out_size, void* d_ws, size_t ws_size,
                              hipStream_t stream) {
  const float* x    = (const float*)d_in[0];
  const float* Wqkv = (const float*)d_in[1];
  const float* bqkv = (const float*)d_in[2];
  const float* Wout = (const float*)d_in[3];
  const float* bout = (const float*)d_in[4];
  float* out = (float*)d_out;

  short* WqkvT = (short*)d_ws;
  short* WoutT = WqkvT + (size_t)NQKV * HIDDEN;
  short* Qb    = WoutT + (size_t)HIDDEN * HIDDEN;
  short* Kb    = Qb + (size_t)BHN * SEQ * HD;
  short* VTb   = Kb + (size_t)BHN * SEQ * HD;
  short* AO    = VTb + (size_t)BHN * SEQ * HD;
  short* Xb    = AO + (size_t)MTOT * HIDDEN;

  cvt_x<<<dim3(MTOT * HIDDEN / (256 * 8)), 256, 0, stream>>>(x, Xb);
  transpose_cvt<<<dim3(NQKV / 64, HIDDEN / 64), 256, 0, stream>>>(Wqkv, WqkvT, HIDDEN, NQKV);
  transpose_cvt<<<dim3(HIDDEN / 64, HIDDEN / 64), 256, 0, stream>>>(Wout, WoutT, HIDDEN, HIDDEN);
  gemm_qkv<<<dim3(MTOT / 128, NQKV / 128), 256, 0, stream>>>(Xb, WqkvT, bqkv, Qb, Kb, VTb);
  attn_fwd<<<dim3(16 * BHN), 256, 0, stream>>>(Qb, Kb, VTb, AO);
  gemm_out<<<dim3(MTOT / 128, HIDDEN / 128), 256, 0, stream>>>(AO, WoutT, bout, out);
}

// Round 5
// 181.829 us; speedup vs baseline: 1.6553x; 1.1314x over previous
//
#include <hip/hip_runtime.h>

typedef __attribute__((ext_vector_type(8))) short short8;
typedef __attribute__((ext_vector_type(4))) short short4v;
typedef __attribute__((ext_vector_type(4))) float floatx4;
typedef __attribute__((ext_vector_type(16))) float floatx16;

#define HIDDEN 768
#define NH 12
#define HD 64
#define SEQ 2048
#define BATCH 2
#define BHN (BATCH*NH)      // 24
#define MTOT (BATCH*SEQ)    // 4096
#define NQKV (3*HIDDEN)     // 2304
#define LDT 40              // BK(32) + 8 pad for the GEMM kernels
#define QSCALE 0.1803368801111204f   // 0.125 * log2(e): scores in log2 domain

__device__ __forceinline__ short f2bf(float f) {
  union { float f; unsigned u; } v; v.f = f;
  unsigned r = v.u + 0x7FFFu + ((v.u >> 16) & 1u);   // RNE
  return (short)(r >> 16);
}
__device__ __forceinline__ unsigned bfrne(float f) {
  unsigned u = __float_as_uint(f);
  return u + 0x7FFFu + ((u >> 16) & 1u);
}
// packed bf16 pair: low16 = bf(a), high16 = bf(b), via v_perm
__device__ __forceinline__ unsigned pk2(float a, float b) {
  return __builtin_amdgcn_perm(bfrne(b), bfrne(a), 0x07060302u);
}
__device__ __forceinline__ float bf2f(short s) {
  return __uint_as_float(((unsigned)(unsigned short)s) << 16);
}
__device__ __forceinline__ floatx4 mfma_bf16(short8 a, short8 b, floatx4 c) {
  return __builtin_amdgcn_mfma_f32_16x16x32_bf16(a, b, c, 0, 0, 0);
}
__device__ __forceinline__ floatx16 mfma32(short8 a, short8 b, floatx16 c) {
  return __builtin_amdgcn_mfma_f32_32x32x16_bf16(a, b, c, 0, 0, 0);
}
__device__ __forceinline__ short8 ld8(const short* p) {
  return *reinterpret_cast<const short8*>(p);
}

// ---------------- weight transpose + fp32->bf16 ----------------
__global__ __launch_bounds__(256) void transpose_cvt(const float* __restrict__ W,
                                                     short* __restrict__ WT,
                                                     int K, int N) {
  __shared__ short t[64][72];
  int nb = blockIdx.x * 64, kb = blockIdx.y * 64;
  int tid = threadIdx.x;
  {
    int k  = tid >> 2;
    int n0 = (tid & 3) << 4;
    const float4* src = reinterpret_cast<const float4*>(W + (size_t)(kb + k) * N + nb + n0);
    #pragma unroll
    for (int c = 0; c < 4; ++c) {
      float4 v = src[c];
      t[n0 + c*4 + 0][k] = f2bf(v.x);
      t[n0 + c*4 + 1][k] = f2bf(v.y);
      t[n0 + c*4 + 2][k] = f2bf(v.z);
      t[n0 + c*4 + 3][k] = f2bf(v.w);
    }
  }
  __syncthreads();
  {
    int n  = tid >> 2;
    int k0 = (tid & 3) << 4;
    const short8* row = reinterpret_cast<const short8*>(&t[n][k0]);
    short8* dst = reinterpret_cast<short8*>(WT + (size_t)(nb + n) * K + kb + k0);
    dst[0] = row[0];
    dst[1] = row[1];
  }
}

// ---------------- X fp32 -> bf16 ----------------
__global__ __launch_bounds__(256) void cvt_x(const float* __restrict__ X,
                                             short* __restrict__ Xb) {
  int i = (blockIdx.x * 256 + threadIdx.x) * 8;
  const float4* s = reinterpret_cast<const float4*>(X + i);
  float4 v0 = s[0], v1 = s[1];
  short8 o;
  o[0] = f2bf(v0.x); o[1] = f2bf(v0.y); o[2] = f2bf(v0.z); o[3] = f2bf(v0.w);
  o[4] = f2bf(v1.x); o[5] = f2bf(v1.y); o[6] = f2bf(v1.z); o[7] = f2bf(v1.w);
  *reinterpret_cast<short8*>(Xb + i) = o;
}

// ---------------- GEMM1 ----------------
__global__ __launch_bounds__(256) void gemm_qkv(const short* __restrict__ Xb,
                                                const short* __restrict__ WT,
                                                const float* __restrict__ bias,
                                                short* __restrict__ Qb,
                                                short* __restrict__ Kb,
                                                short* __restrict__ VTb) {
  __shared__ short As[128 * LDT];
  __shared__ short Bs[128 * LDT];
  int m0 = blockIdx.x * 128, n0 = blockIdx.y * 128;
  int tid = threadIdx.x;
  int lane = tid & 63, wv = tid >> 6;
  int wm = (wv >> 1) << 6, wn = (wv & 1) << 6;
  int quad = lane >> 4, l16 = lane & 15;
  floatx4 acc[4][4] = {};
  for (int kk = 0; kk < HIDDEN; kk += 32) {
    __syncthreads();
    #pragma unroll
    for (int c = 0; c < 2; ++c) {
      int idx = (tid + c * 256) * 8;
      int r = idx >> 5, col = idx & 31;
      *reinterpret_cast<short8*>(&As[r * LDT + col]) =
          ld8(Xb + (size_t)(m0 + r) * HIDDEN + kk + col);
      *reinterpret_cast<short8*>(&Bs[r * LDT + col]) =
          ld8(WT + (size_t)(n0 + r) * HIDDEN + kk + col);
    }
    __syncthreads();
    short8 af[4], bfr[4];
    #pragma unroll
    for (int i = 0; i < 4; ++i)
      af[i] = *reinterpret_cast<const short8*>(&As[(wm + i * 16 + l16) * LDT + quad * 8]);
    #pragma unroll
    for (int j = 0; j < 4; ++j)
      bfr[j] = *reinterpret_cast<const short8*>(&Bs[(wn + j * 16 + l16) * LDT + quad * 8]);
    #pragma unroll
    for (int i = 0; i < 4; ++i)
      #pragma unroll
      for (int j = 0; j < 4; ++j)
        acc[i][j] = mfma_bf16(af[i], bfr[j], acc[i][j]);
  }
  int colbase = n0 + wn;
  int part = colbase / HIDDEN;
  #pragma unroll
  for (int j = 0; j < 4; ++j) {
    int col = colbase + j * 16 + l16;
    float bs = bias[col];
    int rem = col - part * HIDDEN;
    int h = rem >> 6, d = rem & 63;
    #pragma unroll
    for (int i = 0; i < 4; ++i) {
      #pragma unroll
      for (int r = 0; r < 4; ++r) {
        int row = m0 + wm + i * 16 + quad * 4 + r;
        float v = acc[i][j][r] + bs;
        int bb = row >> 11, s = row & 2047;
        int bh = bb * NH + h;
        if (part == 0) {
          Qb[((size_t)bh * SEQ + s) * HD + d] = f2bf(v * QSCALE);
        } else if (part == 1) {
          Kb[((size_t)bh * SEQ + s) * HD + d] = f2bf(v);
        } else {
          VTb[((size_t)bh * HD + d) * SEQ + s] = f2bf(v);
        }
      }
    }
  }
}

// ---------------- flash attention partials: uniform 512-kv chunks ----------------
// Block = (head, 128-q tile, kv-chunk of <=8 64-kv tiles). 4 waves x 32 q,
// LDS double-buffered K/V^T staging, 32x32 MFMA, scores in log2 domain.
// Writes unnormalized O^T (bf16) + m,l per q-row; attn_merge combines chunks.
// 960 blocks, XCD-affine (blk&7 -> 3 heads), heavy chunks first.
__global__ __launch_bounds__(256, 4) void attn_partial(const short* __restrict__ Qb,
                                                       const short* __restrict__ Kb,
                                                       const short* __restrict__ VTb,
                                                       short* __restrict__ PO,
                                                       float* __restrict__ PM,
                                                       float* __restrict__ PL) {
  __shared__ __align__(16) char lds[32768];   // K: buf*8192 ; V: 16384 + buf*8192
  int blk = blockIdx.x;
  int cls = blk & 7;
  int j   = blk >> 3;            // 0..119
  int headsel = j / 40;
  int bh  = cls + 8 * headsel;
  int cidx = 39 - (j - headsel * 40);   // heavy first
  int qt, c;
  if (cidx < 4)       { qt = cidx;                  c = 0; }
  else if (cidx < 12) { qt = 4 + ((cidx - 4) >> 1); c = (cidx - 4) & 1; }
  else if (cidx < 24) { int t = cidx - 12; int q3 = t / 3; qt = 8 + q3; c = t - 3 * q3; }
  else                { int t = cidx - 24; qt = 12 + (t >> 2); c = t & 3; }
  int g = qt >> 2, p = qt & 3;
  int idx = bh * 40 + (g + 1) * (2 * g + p) + c;   // partial slot

  int nt  = 2 * qt + 2;
  int kt0 = c * 8;
  int kt1 = min(nt, kt0 + 8);
  int qb0 = qt * 128;

  int tid = threadIdx.x;
  int lane = tid & 63, wv = tid >> 6;
  int l31 = lane & 31, h = lane >> 5, x = lane & 7;
  const short* Qp = Qb + (size_t)bh * SEQ * HD;
  const short* Kp = Kb + (size_t)bh * SEQ * HD;
  const short* Vp = VTb + (size_t)bh * HD * SEQ;

  int qs  = qb0 + wv * 32 + l31;
  int qlo = qb0 + wv * 32;
  int qhi = qlo + 31;

  short8 bq[4];
  #pragma unroll
  for (int dc = 0; dc < 4; ++dc)
    bq[dc] = ld8(Qp + qs * HD + dc * 16 + h * 8);

  int sr = tid >> 2, scg = tid & 3;
  const short* kg = Kp + (kt0 * 64 + sr) * HD + scg * 16;
  const short* vg = Vp + (size_t)sr * SEQ + kt0 * 64 + scg * 16;
  int wbase = (sr << 7) | (((scg << 1) ^ (sr & 7)) << 4);

  int rbase[4];
  #pragma unroll
  for (int kc = 0; kc < 4; ++kc)
    rbase[kc] = (l31 << 7) | ((((kc << 1) | h) ^ x) << 4);

  // prologue: stage tile kt0 into buf 0
  {
    short8 k0 = ld8(kg), k1 = ld8(kg + 8);
    short8 v0 = ld8(vg), v1 = ld8(vg + 8);
    *reinterpret_cast<short8*>(lds + wbase)                = k0;
    *reinterpret_cast<short8*>(lds + (wbase ^ 16))         = k1;
    *reinterpret_cast<short8*>(lds + 16384 + wbase)        = v0;
    *reinterpret_cast<short8*>(lds + 16384 + (wbase ^ 16)) = v1;
  }
  __syncthreads();

  floatx16 o0 = {}, o1 = {};
  float m_run = -1e30f, l_run = 0.f;

  for (int kt = kt0; kt < kt1; ++kt) {
    int cur = (kt - kt0) & 1;
    int curK = cur * 8192, curV = 16384 + cur * 8192;
    int kb = kt * 64;
    bool have_next = (kt + 1 < kt1);

    short8 nk0, nk1, nv0, nv1;
    if (have_next) {
      kg += 64 * HD; vg += 64;
      nk0 = ld8(kg); nk1 = ld8(kg + 8);
      nv0 = ld8(vg); nv1 = ld8(vg + 8);
    }

    if (kb <= qhi) {
      floatx16 s0 = {}, s1 = {};
      #pragma unroll
      for (int kc = 0; kc < 4; ++kc) {
        short8 ka0 = *reinterpret_cast<const short8*>(lds + curK + rbase[kc]);
        short8 ka1 = *reinterpret_cast<const short8*>(lds + curK + 4096 + rbase[kc]);
        s0 = mfma32(ka0, bq[kc], s0);
        s1 = mfma32(ka1, bq[kc], s1);
      }
      if (kb + 63 > qlo) {   // diagonal crossing: mask
        #pragma unroll
        for (int r = 0; r < 16; ++r) {
          int kvr = kb + (r & 3) + 8 * (r >> 2) + 4 * h;
          s0[r] = (kvr > qs) ? -1e30f : s0[r];
          s1[r] = (kvr + 32 > qs) ? -1e30f : s1[r];
        }
      }
      float mloc = m_run;
      #pragma unroll
      for (int r = 0; r < 16; ++r) { mloc = fmaxf(mloc, s0[r]); mloc = fmaxf(mloc, s1[r]); }
      mloc = fmaxf(mloc, __shfl_xor(mloc, 32));
      float m_new = mloc;
      float alpha = __builtin_amdgcn_exp2f(m_run - m_new);
      float sloc = 0.f;
      #pragma unroll
      for (int r = 0; r < 16; ++r) {
        s0[r] = __builtin_amdgcn_exp2f(s0[r] - m_new); sloc += s0[r];
        s1[r] = __builtin_amdgcn_exp2f(s1[r] - m_new); sloc += s1[r];
      }
      sloc += __shfl_xor(sloc, 32);
      l_run = l_run * alpha + sloc;
      m_run = m_new;
      o0 *= alpha; o1 *= alpha;
      // remap P^T -> B-operand frags via one lane-bit exchange (packed)
      short8 pb[4];
      #pragma unroll
      for (int kvc = 0; kvc < 4; ++kvc) {
        int base = (kvc & 1) * 8;
        const floatx16& P = (kvc < 2) ? s0 : s1;
        unsigned e0 = pk2(P[base + 0], P[base + 1]);
        unsigned e1 = pk2(P[base + 2], P[base + 3]);
        unsigned f0 = pk2(P[base + 4], P[base + 5]);
        unsigned f1 = pk2(P[base + 6], P[base + 7]);
        unsigned k_0 = h ? f0 : e0, k_1 = h ? f1 : e1;
        unsigned s_0 = h ? e0 : f0, s_1 = h ? e1 : f1;
        unsigned r_0 = __shfl_xor((int)s_0, 32);
        unsigned r_1 = __shfl_xor((int)s_1, 32);
        union { unsigned u[4]; short8 v; } pbu;
        pbu.u[0] = h ? r_0 : k_0;
        pbu.u[1] = h ? r_1 : k_1;
        pbu.u[2] = h ? k_0 : r_0;
        pbu.u[3] = h ? k_1 : r_1;
        pb[kvc] = pbu.v;
      }
      #pragma unroll
      for (int kvc = 0; kvc < 4; ++kvc) {
        short8 va0 = *reinterpret_cast<const short8*>(lds + curV + rbase[kvc]);
        short8 va1 = *reinterpret_cast<const short8*>(lds + curV + 4096 + rbase[kvc]);
        o0 = mfma32(va0, pb[kvc], o0);
        o1 = mfma32(va1, pb[kvc], o1);
      }
    }

    if (have_next) {
      int nK = (cur ^ 1) * 8192, nV = 16384 + (cur ^ 1) * 8192;
      *reinterpret_cast<short8*>(lds + nK + wbase)        = nk0;
      *reinterpret_cast<short8*>(lds + nK + (wbase ^ 16)) = nk1;
      *reinterpret_cast<short8*>(lds + nV + wbase)        = nv0;
      *reinterpret_cast<short8*>(lds + nV + (wbase ^ 16)) = nv1;
    }
    __syncthreads();
  }

  // ---- epilogue: unnormalized partial O^T + (m,l) ----
  int qloc = wv * 32 + l31;
  size_t pobase = (size_t)idx * 8192 + qloc * 64;
  #pragma unroll
  for (int dt = 0; dt < 2; ++dt) {
    #pragma unroll
    for (int cc = 0; cc < 4; ++cc) {
      int d = dt * 32 + 8 * cc + 4 * h;
      short4v w;
      #pragma unroll
      for (int r = 0; r < 4; ++r)
        w[r] = f2bf(dt ? o1[4 * cc + r] : o0[4 * cc + r]);
      *reinterpret_cast<short4v*>(PO + pobase + d) = w;
    }
  }
  if (h == 0) {
    PM[idx * 128 + qloc] = m_run;
    PL[idx * 128 + qloc] = l_run;
  }
}

// ---------------- merge partial chunks -> AO ----------------
// Grid (24*16), 256 threads: thread = (q, d-half of 32).
__global__ __launch_bounds__(256) void attn_merge(const short* __restrict__ PO,
                                                  const float* __restrict__ PM,
                                                  const float* __restrict__ PL,
                                                  short* __restrict__ AO) {
  int blk = blockIdx.x;
  int bh = blk >> 4, qt = blk & 15;
  int g = qt >> 2, p = qt & 3;
  int base = bh * 40 + (g + 1) * (2 * g + p);
  int nc = g + 1;
  int tid = threadIdx.x;
  int q = tid >> 1, dh = (tid & 1) << 5;
  float mv[4];
  float M = -1e30f;
  for (int c = 0; c < nc; ++c) {
    mv[c] = PM[(base + c) * 128 + q];
    M = fmaxf(M, mv[c]);
  }
  float wsum = 0.f;
  float acc[32] = {};
  for (int c = 0; c < nc; ++c) {
    float w = __builtin_amdgcn_exp2f(mv[c] - M);
    wsum += PL[(base + c) * 128 + q] * w;
    const short8* po = reinterpret_cast<const short8*>(PO + (size_t)(base + c) * 8192 + q * 64 + dh);
    #pragma unroll
    for (int k = 0; k < 4; ++k) {
      short8 v = po[k];
      #pragma unroll
      for (int e = 0; e < 8; ++e)
        acc[k * 8 + e] += w * bf2f(v[e]);
    }
  }
  float inv = 1.f / wsum;
  int b = bh / NH, hh = bh % NH;
  int s = qt * 128 + q;
  short* dst = AO + ((size_t)(b * SEQ + s)) * HIDDEN + hh * HD + dh;
  #pragma unroll
  for (int k = 0; k < 4; ++k) {
    short8 w8;
    #pragma unroll
    for (int e = 0; e < 8; ++e)
      w8[e] = f2bf(acc[k * 8 + e] * inv);
    *reinterpret_cast<short8*>(dst + k * 8) = w8;
  }
}

// ---------------- GEMM2 ----------------
__global__ __launch_bounds__(256) void gemm_out(const short* __restrict__ AO,
                                                const short* __restrict__ WT,
                                                const float* __restrict__ bias,
                                                float* __restrict__ out) {
  __shared__ short As[128 * LDT];
  __shared__ short Bs[128 * LDT];
  int m0 = blockIdx.x * 128, n0 = blockIdx.y * 128;
  int tid = threadIdx.x;
  int lane = tid & 63, wv = tid >> 6;
  int wm = (wv >> 1) << 6, wn = (wv & 1) << 6;
  int quad = lane >> 4, l16 = lane & 15;
  floatx4 acc[4][4] = {};
  for (int kk = 0; kk < HIDDEN; kk += 32) {
    __syncthreads();
    #pragma unroll
    for (int c = 0; c < 2; ++c) {
      int idx = (tid + c * 256) * 8;
      int r = idx >> 5, col = idx & 31;
      *reinterpret_cast<short8*>(&As[r * LDT + col]) =
          ld8(AO + (size_t)(m0 + r) * HIDDEN + kk + col);
      *reinterpret_cast<short8*>(&Bs[r * LDT + col]) =
          ld8(WT + (size_t)(n0 + r) * HIDDEN + kk + col);
    }
    __syncthreads();
    short8 af[4], bfr[4];
    #pragma unroll
    for (int i = 0; i < 4; ++i)
      af[i] = *reinterpret_cast<const short8*>(&As[(wm + i * 16 + l16) * LDT + quad * 8]);
    #pragma unroll
    for (int j = 0; j < 4; ++j)
      bfr[j] = *reinterpret_cast<const short8*>(&Bs[(wn + j * 16 + l16) * LDT + quad * 8]);
    #pragma unroll
    for (int i = 0; i < 4; ++i)
      #pragma unroll
      for (int j = 0; j < 4; ++j)
        acc[i][j] = mfma_bf16(af[i], bfr[j], acc[i][j]);
  }
  #pragma unroll
  for (int j = 0; j < 4; ++j) {
    int col = n0 + wn + j * 16 + l16;
    float bs = bias[col];
    #pragma unroll
    for (int i = 0; i < 4; ++i) {
      #pragma unroll
      for (int r = 0; r < 4; ++r) {
        int row = m0 + wm + i * 16 + quad * 4 + r;
        out[(size_t)row * HIDDEN + col] = acc[i][j][r] + bs;
      }
    }
  }
}

extern "C" void kernel_launch(void* const* d_in, const int* in_sizes, int n_in,
                              void* d_out, int out_size, void* d_ws, size_t ws_size,
                              hipStream_t stream) {
  const float* x    = (const float*)d_in[0];
  const float* Wqkv = (const float*)d_in[1];
  const float* bqkv = (const float*)d_in[2];
  const float* Wout = (const float*)d_in[3];
  const float* bout = (const float*)d_in[4];
  float* out = (float*)d_out;

  short* WqkvT = (short*)d_ws;                     // [2304][768]
  short* WoutT = WqkvT + (size_t)NQKV * HIDDEN;    // [768][768]
  short* Qb    = WoutT + (size_t)HIDDEN * HIDDEN;  // [24][2048][64] (log2-domain scale)
  short* Kb    = Qb + (size_t)BHN * SEQ * HD;
  short* VTb   = Kb + (size_t)BHN * SEQ * HD;      // [24][64][2048]
  short* AO    = VTb + (size_t)BHN * SEQ * HD;     // [4096][768]
  short* Xb    = AO + (size_t)MTOT * HIDDEN;       // [4096][768] (dead after gemm_qkv)
  short* PO    = Xb;                               // aliases Xb: 960*8192 bf16 partials
  float* PM    = (float*)(PO + (size_t)960 * 8192);
  float* PL    = PM + 960 * 128;
  // total ws: ~46.6 MB

  cvt_x<<<dim3(MTOT * HIDDEN / (256 * 8)), 256, 0, stream>>>(x, Xb);
  transpose_cvt<<<dim3(NQKV / 64, HIDDEN / 64), 256, 0, stream>>>(Wqkv, WqkvT, HIDDEN, NQKV);
  transpose_cvt<<<dim3(HIDDEN / 64, HIDDEN / 64), 256, 0, stream>>>(Wout, WoutT, HIDDEN, HIDDEN);
  gemm_qkv<<<dim3(MTOT / 128, NQKV / 128), 256, 0, stream>>>(Xb, WqkvT, bqkv, Qb, Kb, VTb);
  attn_partial<<<dim3(960), 256, 0, stream>>>(Qb, Kb, VTb, PO, PM, PL);
  attn_merge<<<dim3(BHN * 16), 256, 0, stream>>>(PO, PM, PL, AO);
  gemm_out<<<dim3(MTOT / 128, HIDDEN / 128), 256, 0, stream>>>(AO, WoutT, bout, out);
}

// Round 6
// 163.282 us; speedup vs baseline: 1.8433x; 1.1136x over previous
//
#include <hip/hip_runtime.h>

typedef __attribute__((ext_vector_type(8))) short short8;
typedef __attribute__((ext_vector_type(4))) short short4v;
typedef __attribute__((ext_vector_type(4))) float floatx4;
typedef __attribute__((ext_vector_type(16))) float floatx16;

#define HIDDEN 768
#define NH 12
#define HD 64
#define SEQ 2048
#define BATCH 2
#define BHN (BATCH*NH)      // 24
#define MTOT (BATCH*SEQ)    // 4096
#define NQKV (3*HIDDEN)     // 2304
#define QSCALE 0.1803368801111204f   // 0.125 * log2(e): scores in log2 domain

__device__ __forceinline__ short f2bf(float f) {
  union { float f; unsigned u; } v; v.f = f;
  unsigned r = v.u + 0x7FFFu + ((v.u >> 16) & 1u);   // RNE
  return (short)(r >> 16);
}
__device__ __forceinline__ unsigned bfrne(float f) {
  unsigned u = __float_as_uint(f);
  return u + 0x7FFFu + ((u >> 16) & 1u);
}
__device__ __forceinline__ unsigned pk2(float a, float b) {
  return __builtin_amdgcn_perm(bfrne(b), bfrne(a), 0x07060302u);
}
__device__ __forceinline__ float bf2f(short s) {
  return __uint_as_float(((unsigned)(unsigned short)s) << 16);
}
__device__ __forceinline__ floatx4 mfma_bf16(short8 a, short8 b, floatx4 c) {
  return __builtin_amdgcn_mfma_f32_16x16x32_bf16(a, b, c, 0, 0, 0);
}
__device__ __forceinline__ floatx16 mfma32(short8 a, short8 b, floatx16 c) {
  return __builtin_amdgcn_mfma_f32_32x32x16_bf16(a, b, c, 0, 0, 0);
}
__device__ __forceinline__ short8 ld8(const short* p) {
  return *reinterpret_cast<const short8*>(p);
}
// async global->LDS DMA, 16B per lane. LDS dst = wave-uniform base + lane*16.
__device__ __forceinline__ void glds16(const short* g, short* l) {
  __builtin_amdgcn_global_load_lds(
      (const __attribute__((address_space(1))) void*)g,
      (__attribute__((address_space(3))) void*)l, 16, 0, 0);
}

// ---------------- weight transpose + fp32->bf16 ----------------
__global__ __launch_bounds__(256) void transpose_cvt(const float* __restrict__ W,
                                                     short* __restrict__ WT,
                                                     int K, int N) {
  __shared__ short t[64][72];
  int nb = blockIdx.x * 64, kb = blockIdx.y * 64;
  int tid = threadIdx.x;
  {
    int k  = tid >> 2;
    int n0 = (tid & 3) << 4;
    const float4* src = reinterpret_cast<const float4*>(W + (size_t)(kb + k) * N + nb + n0);
    #pragma unroll
    for (int c = 0; c < 4; ++c) {
      float4 v = src[c];
      t[n0 + c*4 + 0][k] = f2bf(v.x);
      t[n0 + c*4 + 1][k] = f2bf(v.y);
      t[n0 + c*4 + 2][k] = f2bf(v.z);
      t[n0 + c*4 + 3][k] = f2bf(v.w);
    }
  }
  __syncthreads();
  {
    int n  = tid >> 2;
    int k0 = (tid & 3) << 4;
    const short8* row = reinterpret_cast<const short8*>(&t[n][k0]);
    short8* dst = reinterpret_cast<short8*>(WT + (size_t)(nb + n) * K + kb + k0);
    dst[0] = row[0];
    dst[1] = row[1];
  }
}

// ---------------- X fp32 -> bf16 ----------------
__global__ __launch_bounds__(256) void cvt_x(const float* __restrict__ X,
                                             short* __restrict__ Xb) {
  int i = (blockIdx.x * 256 + threadIdx.x) * 8;
  const float4* s = reinterpret_cast<const float4*>(X + i);
  float4 v0 = s[0], v1 = s[1];
  short8 o;
  o[0] = f2bf(v0.x); o[1] = f2bf(v0.y); o[2] = f2bf(v0.z); o[3] = f2bf(v0.w);
  o[4] = f2bf(v1.x); o[5] = f2bf(v1.y); o[6] = f2bf(v1.z); o[7] = f2bf(v1.w);
  *reinterpret_cast<short8*>(Xb + i) = o;
}

// ---------------- GEMM1: global_load_lds staging, XOR-swizzled LDS ----------------
// LDS tile: 128 rows x 32 shorts (64B = 4x16B chunks). Slot (row,c) holds global
// chunk c ^ ((row>>1)&3)  -> frag ds_read_b128 is 2-way max per phase (free).
// Each wave DMAs its 32 rows of A and B (4 x glds16 per K-step). m97 structure.
__global__ __launch_bounds__(256) void gemm_qkv(const short* __restrict__ Xb,
                                                const short* __restrict__ WT,
                                                const float* __restrict__ bias,
                                                short* __restrict__ Qb,
                                                short* __restrict__ Kb,
                                                short* __restrict__ VTb) {
  __shared__ short As[128 * 32];
  __shared__ short Bs[128 * 32];
  int m0 = blockIdx.x * 128, n0 = blockIdx.y * 128;
  int tid = threadIdx.x;
  int lane = tid & 63, wv = tid >> 6;
  int wm = (wv >> 1) << 6, wn = (wv & 1) << 6;
  int quad = lane >> 4, l16 = lane & 15;

  // staging: lane l -> row (l>>2), global chunk (l&3)^((l>>3)&3)
  int srow = lane >> 2;
  int schunk = (lane & 3) ^ ((lane >> 3) & 3);
  const short* ag0 = Xb + (size_t)(m0 + wv * 32 + srow) * HIDDEN + schunk * 8;
  const short* ag1 = ag0 + 16 * HIDDEN;
  const short* bg0 = WT + (size_t)(n0 + wv * 32 + srow) * HIDDEN + schunk * 8;
  const short* bg1 = bg0 + 16 * HIDDEN;
  short* lA0 = As + wv * 1024;
  short* lB0 = Bs + wv * 1024;

  // frag read offsets (shorts): row*32 + (quad ^ ((l16>>1)&3))*8
  int sw = ((l16 >> 1) & 3);
  int aoff = (wm + l16) * 32 + ((quad ^ sw) << 3);
  int boff = (wn + l16) * 32 + ((quad ^ sw) << 3);

  floatx4 acc[4][4] = {};
  for (int kk = 0; kk < HIDDEN; kk += 32) {
    __syncthreads();
    glds16(ag0, lA0);
    glds16(ag1, lA0 + 512);
    glds16(bg0, lB0);
    glds16(bg1, lB0 + 512);
    ag0 += 32; ag1 += 32; bg0 += 32; bg1 += 32;
    __syncthreads();
    short8 af[4], bfr[4];
    #pragma unroll
    for (int i = 0; i < 4; ++i)
      af[i] = *reinterpret_cast<const short8*>(&As[aoff + i * 512]);
    #pragma unroll
    for (int j = 0; j < 4; ++j)
      bfr[j] = *reinterpret_cast<const short8*>(&Bs[boff + j * 512]);
    #pragma unroll
    for (int i = 0; i < 4; ++i)
      #pragma unroll
      for (int j = 0; j < 4; ++j)
        acc[i][j] = mfma_bf16(af[i], bfr[j], acc[i][j]);
  }
  int colbase = n0 + wn;
  int part = colbase / HIDDEN;
  #pragma unroll
  for (int j = 0; j < 4; ++j) {
    int col = colbase + j * 16 + l16;
    float bs = bias[col];
    int rem = col - part * HIDDEN;
    int h = rem >> 6, d = rem & 63;
    #pragma unroll
    for (int i = 0; i < 4; ++i) {
      #pragma unroll
      for (int r = 0; r < 4; ++r) {
        int row = m0 + wm + i * 16 + quad * 4 + r;
        float v = acc[i][j][r] + bs;
        int bb = row >> 11, s = row & 2047;
        int bh = bb * NH + h;
        if (part == 0) {
          Qb[((size_t)bh * SEQ + s) * HD + d] = f2bf(v * QSCALE);
        } else if (part == 1) {
          Kb[((size_t)bh * SEQ + s) * HD + d] = f2bf(v);
        } else {
          VTb[((size_t)bh * HD + d) * SEQ + s] = f2bf(v);
        }
      }
    }
  }
}

// ---------------- flash attention partials: uniform 512-kv chunks ----------------
__global__ __launch_bounds__(256, 4) void attn_partial(const short* __restrict__ Qb,
                                                       const short* __restrict__ Kb,
                                                       const short* __restrict__ VTb,
                                                       short* __restrict__ PO,
                                                       float* __restrict__ PM,
                                                       float* __restrict__ PL) {
  __shared__ __align__(16) char lds[32768];   // K: buf*8192 ; V: 16384 + buf*8192
  int blk = blockIdx.x;
  int cls = blk & 7;
  int j   = blk >> 3;            // 0..119
  int headsel = j / 40;
  int bh  = cls + 8 * headsel;
  int cidx = 39 - (j - headsel * 40);   // heavy first
  int qt, c;
  if (cidx < 4)       { qt = cidx;                  c = 0; }
  else if (cidx < 12) { qt = 4 + ((cidx - 4) >> 1); c = (cidx - 4) & 1; }
  else if (cidx < 24) { int t = cidx - 12; int q3 = t / 3; qt = 8 + q3; c = t - 3 * q3; }
  else                { int t = cidx - 24; qt = 12 + (t >> 2); c = t & 3; }
  int g = qt >> 2, p = qt & 3;
  int idx = bh * 40 + (g + 1) * (2 * g + p) + c;   // partial slot

  int nt  = 2 * qt + 2;
  int kt0 = c * 8;
  int kt1 = min(nt, kt0 + 8);
  int qb0 = qt * 128;

  int tid = threadIdx.x;
  int lane = tid & 63, wv = tid >> 6;
  int l31 = lane & 31, h = lane >> 5, x = lane & 7;
  const short* Qp = Qb + (size_t)bh * SEQ * HD;
  const short* Kp = Kb + (size_t)bh * SEQ * HD;
  const short* Vp = VTb + (size_t)bh * HD * SEQ;

  int qs  = qb0 + wv * 32 + l31;
  int qlo = qb0 + wv * 32;
  int qhi = qlo + 31;

  short8 bq[4];
  #pragma unroll
  for (int dc = 0; dc < 4; ++dc)
    bq[dc] = ld8(Qp + qs * HD + dc * 16 + h * 8);

  int sr = tid >> 2, scg = tid & 3;
  const short* kg = Kp + (kt0 * 64 + sr) * HD + scg * 16;
  const short* vg = Vp + (size_t)sr * SEQ + kt0 * 64 + scg * 16;
  int wbase = (sr << 7) | (((scg << 1) ^ (sr & 7)) << 4);

  int rbase[4];
  #pragma unroll
  for (int kc = 0; kc < 4; ++kc)
    rbase[kc] = (l31 << 7) | ((((kc << 1) | h) ^ x) << 4);

  {
    short8 k0 = ld8(kg), k1 = ld8(kg + 8);
    short8 v0 = ld8(vg), v1 = ld8(vg + 8);
    *reinterpret_cast<short8*>(lds + wbase)                = k0;
    *reinterpret_cast<short8*>(lds + (wbase ^ 16))         = k1;
    *reinterpret_cast<short8*>(lds + 16384 + wbase)        = v0;
    *reinterpret_cast<short8*>(lds + 16384 + (wbase ^ 16)) = v1;
  }
  __syncthreads();

  floatx16 o0 = {}, o1 = {};
  float m_run = -1e30f, l_run = 0.f;

  for (int kt = kt0; kt < kt1; ++kt) {
    int cur = (kt - kt0) & 1;
    int curK = cur * 8192, curV = 16384 + cur * 8192;
    int kb = kt * 64;
    bool have_next = (kt + 1 < kt1);

    short8 nk0, nk1, nv0, nv1;
    if (have_next) {
      kg += 64 * HD; vg += 64;
      nk0 = ld8(kg); nk1 = ld8(kg + 8);
      nv0 = ld8(vg); nv1 = ld8(vg + 8);
    }

    if (kb <= qhi) {
      floatx16 s0 = {}, s1 = {};
      #pragma unroll
      for (int kc = 0; kc < 4; ++kc) {
        short8 ka0 = *reinterpret_cast<const short8*>(lds + curK + rbase[kc]);
        short8 ka1 = *reinterpret_cast<const short8*>(lds + curK + 4096 + rbase[kc]);
        s0 = mfma32(ka0, bq[kc], s0);
        s1 = mfma32(ka1, bq[kc], s1);
      }
      if (kb + 63 > qlo) {
        #pragma unroll
        for (int r = 0; r < 16; ++r) {
          int kvr = kb + (r & 3) + 8 * (r >> 2) + 4 * h;
          s0[r] = (kvr > qs) ? -1e30f : s0[r];
          s1[r] = (kvr + 32 > qs) ? -1e30f : s1[r];
        }
      }
      float mloc = m_run;
      #pragma unroll
      for (int r = 0; r < 16; ++r) { mloc = fmaxf(mloc, s0[r]); mloc = fmaxf(mloc, s1[r]); }
      mloc = fmaxf(mloc, __shfl_xor(mloc, 32));
      float m_new = mloc;
      float alpha = __builtin_amdgcn_exp2f(m_run - m_new);
      float sloc = 0.f;
      #pragma unroll
      for (int r = 0; r < 16; ++r) {
        s0[r] = __builtin_amdgcn_exp2f(s0[r] - m_new); sloc += s0[r];
        s1[r] = __builtin_amdgcn_exp2f(s1[r] - m_new); sloc += s1[r];
      }
      sloc += __shfl_xor(sloc, 32);
      l_run = l_run * alpha + sloc;
      m_run = m_new;
      o0 *= alpha; o1 *= alpha;
      short8 pb[4];
      #pragma unroll
      for (int kvc = 0; kvc < 4; ++kvc) {
        int base = (kvc & 1) * 8;
        const floatx16& P = (kvc < 2) ? s0 : s1;
        unsigned e0 = pk2(P[base + 0], P[base + 1]);
        unsigned e1 = pk2(P[base + 2], P[base + 3]);
        unsigned f0 = pk2(P[base + 4], P[base + 5]);
        unsigned f1 = pk2(P[base + 6], P[base + 7]);
        unsigned k_0 = h ? f0 : e0, k_1 = h ? f1 : e1;
        unsigned s_0 = h ? e0 : f0, s_1 = h ? e1 : f1;
        unsigned r_0 = __shfl_xor((int)s_0, 32);
        unsigned r_1 = __shfl_xor((int)s_1, 32);
        union { unsigned u[4]; short8 v; } pbu;
        pbu.u[0] = h ? r_0 : k_0;
        pbu.u[1] = h ? r_1 : k_1;
        pbu.u[2] = h ? k_0 : r_0;
        pbu.u[3] = h ? k_1 : r_1;
        pb[kvc] = pbu.v;
      }
      #pragma unroll
      for (int kvc = 0; kvc < 4; ++kvc) {
        short8 va0 = *reinterpret_cast<const short8*>(lds + curV + rbase[kvc]);
        short8 va1 = *reinterpret_cast<const short8*>(lds + curV + 4096 + rbase[kvc]);
        o0 = mfma32(va0, pb[kvc], o0);
        o1 = mfma32(va1, pb[kvc], o1);
      }
    }

    if (have_next) {
      int nK = (cur ^ 1) * 8192, nV = 16384 + (cur ^ 1) * 8192;
      *reinterpret_cast<short8*>(lds + nK + wbase)        = nk0;
      *reinterpret_cast<short8*>(lds + nK + (wbase ^ 16)) = nk1;
      *reinterpret_cast<short8*>(lds + nV + wbase)        = nv0;
      *reinterpret_cast<short8*>(lds + nV + (wbase ^ 16)) = nv1;
    }
    __syncthreads();
  }

  int qloc = wv * 32 + l31;
  size_t pobase = (size_t)idx * 8192 + qloc * 64;
  #pragma unroll
  for (int dt = 0; dt < 2; ++dt) {
    #pragma unroll
    for (int cc = 0; cc < 4; ++cc) {
      int d = dt * 32 + 8 * cc + 4 * h;
      short4v w;
      #pragma unroll
      for (int r = 0; r < 4; ++r)
        w[r] = f2bf(dt ? o1[4 * cc + r] : o0[4 * cc + r]);
      *reinterpret_cast<short4v*>(PO + pobase + d) = w;
    }
  }
  if (h == 0) {
    PM[idx * 128 + qloc] = m_run;
    PL[idx * 128 + qloc] = l_run;
  }
}

// ---------------- merge partial chunks -> AO ----------------
__global__ __launch_bounds__(256) void attn_merge(const short* __restrict__ PO,
                                                  const float* __restrict__ PM,
                                                  const float* __restrict__ PL,
                                                  short* __restrict__ AO) {
  int blk = blockIdx.x;
  int bh = blk >> 4, qt = blk & 15;
  int g = qt >> 2, p = qt & 3;
  int base = bh * 40 + (g + 1) * (2 * g + p);
  int nc = g + 1;
  int tid = threadIdx.x;
  int q = tid >> 1, dh = (tid & 1) << 5;
  float mv[4];
  float M = -1e30f;
  for (int c = 0; c < nc; ++c) {
    mv[c] = PM[(base + c) * 128 + q];
    M = fmaxf(M, mv[c]);
  }
  float wsum = 0.f;
  float acc[32] = {};
  for (int c = 0; c < nc; ++c) {
    float w = __builtin_amdgcn_exp2f(mv[c] - M);
    wsum += PL[(base + c) * 128 + q] * w;
    const short8* po = reinterpret_cast<const short8*>(PO + (size_t)(base + c) * 8192 + q * 64 + dh);
    #pragma unroll
    for (int k = 0; k < 4; ++k) {
      short8 v = po[k];
      #pragma unroll
      for (int e = 0; e < 8; ++e)
        acc[k * 8 + e] += w * bf2f(v[e]);
    }
  }
  float inv = 1.f / wsum;
  int b = bh / NH, hh = bh % NH;
  int s = qt * 128 + q;
  short* dst = AO + ((size_t)(b * SEQ + s)) * HIDDEN + hh * HD + dh;
  #pragma unroll
  for (int k = 0; k < 4; ++k) {
    short8 w8;
    #pragma unroll
    for (int e = 0; e < 8; ++e)
      w8[e] = f2bf(acc[k * 8 + e] * inv);
    *reinterpret_cast<short8*>(dst + k * 8) = w8;
  }
}

// ---------------- GEMM2: same global_load_lds structure ----------------
__global__ __launch_bounds__(256) void gemm_out(const short* __restrict__ AO,
                                                const short* __restrict__ WT,
                                                const float* __restrict__ bias,
                                                float* __restrict__ out) {
  __shared__ short As[128 * 32];
  __shared__ short Bs[128 * 32];
  int m0 = blockIdx.x * 128, n0 = blockIdx.y * 128;
  int tid = threadIdx.x;
  int lane = tid & 63, wv = tid >> 6;
  int wm = (wv >> 1) << 6, wn = (wv & 1) << 6;
  int quad = lane >> 4, l16 = lane & 15;

  int srow = lane >> 2;
  int schunk = (lane & 3) ^ ((lane >> 3) & 3);
  const short* ag0 = AO + (size_t)(m0 + wv * 32 + srow) * HIDDEN + schunk * 8;
  const short* ag1 = ag0 + 16 * HIDDEN;
  const short* bg0 = WT + (size_t)(n0 + wv * 32 + srow) * HIDDEN + schunk * 8;
  const short* bg1 = bg0 + 16 * HIDDEN;
  short* lA0 = As + wv * 1024;
  short* lB0 = Bs + wv * 1024;

  int sw = ((l16 >> 1) & 3);
  int aoff = (wm + l16) * 32 + ((quad ^ sw) << 3);
  int boff = (wn + l16) * 32 + ((quad ^ sw) << 3);

  floatx4 acc[4][4] = {};
  for (int kk = 0; kk < HIDDEN; kk += 32) {
    __syncthreads();
    glds16(ag0, lA0);
    glds16(ag1, lA0 + 512);
    glds16(bg0, lB0);
    glds16(bg1, lB0 + 512);
    ag0 += 32; ag1 += 32; bg0 += 32; bg1 += 32;
    __syncthreads();
    short8 af[4], bfr[4];
    #pragma unroll
    for (int i = 0; i < 4; ++i)
      af[i] = *reinterpret_cast<const short8*>(&As[aoff + i * 512]);
    #pragma unroll
    for (int j = 0; j < 4; ++j)
      bfr[j] = *reinterpret_cast<const short8*>(&Bs[boff + j * 512]);
    #pragma unroll
    for (int i = 0; i < 4; ++i)
      #pragma unroll
      for (int j = 0; j < 4; ++j)
        acc[i][j] = mfma_bf16(af[i], bfr[j], acc[i][j]);
  }
  #pragma unroll
  for (int j = 0; j < 4; ++j) {
    int col = n0 + wn + j * 16 + l16;
    float bs = bias[col];
    #pragma unroll
    for (int i = 0; i < 4; ++i) {
      #pragma unroll
      for (int r = 0; r < 4; ++r) {
        int row = m0 + wm + i * 16 + quad * 4 + r;
        out[(size_t)row * HIDDEN + col] = acc[i][j][r] + bs;
      }
    }
  }
}

extern "C" void kernel_launch(void* const* d_in, const int* in_sizes, int n_in,
                              void* d_out, int out_size, void* d_ws, size_t ws_size,
                              hipStream_t stream) {
  const float* x    = (const float*)d_in[0];
  const float* Wqkv = (const float*)d_in[1];
  const float* bqkv = (const float*)d_in[2];
  const float* Wout = (const float*)d_in[3];
  const float* bout = (const float*)d_in[4];
  float* out = (float*)d_out;

  short* WqkvT = (short*)d_ws;                     // [2304][768]
  short* WoutT = WqkvT + (size_t)NQKV * HIDDEN;    // [768][768]
  short* Qb    = WoutT + (size_t)HIDDEN * HIDDEN;  // [24][2048][64] (log2-domain scale)
  short* Kb    = Qb + (size_t)BHN * SEQ * HD;
  short* VTb   = Kb + (size_t)BHN * SEQ * HD;      // [24][64][2048]
  short* AO    = VTb + (size_t)BHN * SEQ * HD;     // [4096][768]
  short* Xb    = AO + (size_t)MTOT * HIDDEN;       // [4096][768] (dead after gemm_qkv)
  short* PO    = Xb;                               // aliases Xb: 960*8192 bf16 partials
  float* PM    = (float*)(PO + (size_t)960 * 8192);
  float* PL    = PM + 960 * 128;

  cvt_x<<<dim3(MTOT * HIDDEN / (256 * 8)), 256, 0, stream>>>(x, Xb);
  transpose_cvt<<<dim3(NQKV / 64, HIDDEN / 64), 256, 0, stream>>>(Wqkv, WqkvT, HIDDEN, NQKV);
  transpose_cvt<<<dim3(HIDDEN / 64, HIDDEN / 64), 256, 0, stream>>>(Wout, WoutT, HIDDEN, HIDDEN);
  gemm_qkv<<<dim3(MTOT / 128, NQKV / 128), 256, 0, stream>>>(Xb, WqkvT, bqkv, Qb, Kb, VTb);
  attn_partial<<<dim3(960), 256, 0, stream>>>(Qb, Kb, VTb, PO, PM, PL);
  attn_merge<<<dim3(BHN * 16), 256, 0, stream>>>(PO, PM, PL, AO);
  gemm_out<<<dim3(MTOT / 128, HIDDEN / 128), 256, 0, stream>>>(AO, WoutT, bout, out);
}